// Round 4
// baseline (3296.328 us; speedup 1.0000x reference)
//
#include <hip/hip_runtime.h>
#include <math.h>

#define HDIM 128
#define G4 512  // 4*H
#define TS 34   // LDS row stride (floats): 34 mod 32 = 2 -> 2-way banks on reads

typedef float vf4 __attribute__((ext_vector_type(4)));

__device__ __forceinline__ float sigm(float v) { return 1.0f / (1.0f + __expf(-v)); }
__device__ __forceinline__ float ftanh(float v) {
    return 1.0f - 2.0f / (__expf(2.0f * v) + 1.0f);
}
__device__ __forceinline__ float dot4(vf4 a, vf4 b) {
    return a.x * b.x + a.y * b.y + a.z * b.z + a.w * b.w;
}

// ---- fused setup: Wc prep + segment starts + step-0 LSTM (gates = bias)
__global__ __launch_bounds__(256) void k_setup(const float* __restrict__ W_ih,
                                               const float* __restrict__ W_hh,
                                               const float* __restrict__ b_ih,
                                               const float* __restrict__ b_hh,
                                               const int* __restrict__ batch_vec, int N, int B,
                                               float* __restrict__ Wc, int* __restrict__ seg_start,
                                               float* __restrict__ h, float* __restrict__ c) {
    int t = blockIdx.x * 256 + threadIdx.x;
    if (t < B * HDIM) {  // step-0 LSTM: h=c=0, gates = b_ih+b_hh
        int hid = t & (HDIM - 1);
        float gi = b_ih[hid] + b_hh[hid];
        float gg = b_ih[2 * HDIM + hid] + b_hh[2 * HDIM + hid];
        float go = b_ih[3 * HDIM + hid] + b_hh[3 * HDIM + hid];
        float cv = sigm(gi) * ftanh(gg);
        c[t] = cv;
        h[t] = sigm(go) * ftanh(cv);
    }
    if (t < G4 * 2 * HDIM) {  // Wc[512][256] = [W_ih[:,:128]+W_hh | W_ih[:,128:]]
        int g = t >> 8;
        int k = t & 255;
        float w = W_ih[g * 256 + k];
        if (k < HDIM) w += W_hh[g * HDIM + k];
        Wc[t] = w;
    }
    if (t <= B) {  // segment starts: lower_bound over sorted batch_vec
        int lo = 0, hi = N;
        while (lo < hi) {
            int mid = (lo + hi) >> 1;
            if (batch_vec[mid] < t) lo = mid + 1; else hi = mid;
        }
        seg_start[t] = lo;
    }
}

// ---- fused attention: one wave/segment, 16 lanes/row x 4 rows, dual online state.
// rev=1 walks segments back-to-front (serpentine scan -> L3 reuse across passes).
#define UPD(m_, d_, ra_, rb_, p_, xa_, xb_)  \
    {                                        \
        float mn_ = fmaxf(m_, p_);           \
        float sc_ = __expf(m_ - mn_);        \
        float pe_ = __expf(p_ - mn_);        \
        d_ = d_ * sc_ + pe_;                 \
        ra_ = ra_ * sc_ + pe_ * xa_;         \
        rb_ = rb_ * sc_ + pe_ * xb_;         \
        m_ = mn_;                            \
    }

__global__ __launch_bounds__(256) void k_attn(const float* __restrict__ x,
                                              const float* __restrict__ q,
                                              const int* __restrict__ seg_start,
                                              float* __restrict__ r_out, int ldr, int col_off,
                                              int B, int rev) {
    int wave = threadIdx.x >> 6;
    int lane = threadIdx.x & 63;
    int l16 = lane & 15;
    int quarter = lane >> 4;
    int gid = (blockIdx.x << 2) + wave;
    if (gid >= B) return;
    int seg = rev ? (B - 1 - gid) : gid;
    int s = seg_start[seg];
    int e = seg_start[seg + 1];

    const float* qrow = q + (size_t)seg * HDIM;
    vf4 qa = *(const vf4*)(qrow + l16 * 4);
    vf4 qb = *(const vf4*)(qrow + 64 + l16 * 4);

    float m0 = 0.0f, d0 = 0.0f, m1 = 0.0f, d1 = 0.0f;
    vf4 ra0 = {0.f, 0.f, 0.f, 0.f}, rb0 = {0.f, 0.f, 0.f, 0.f};
    vf4 ra1 = {0.f, 0.f, 0.f, 0.f}, rb1 = {0.f, 0.f, 0.f, 0.f};

    int base = s;
#pragma unroll 2
    for (; base + 8 <= e; base += 8) {
        const float* xr0 = x + (size_t)(base + quarter) * HDIM;
        const float* xr1 = xr0 + 4 * HDIM;
        vf4 xa0 = *(const vf4*)(xr0 + l16 * 4), xb0 = *(const vf4*)(xr0 + 64 + l16 * 4);
        vf4 xa1 = *(const vf4*)(xr1 + l16 * 4), xb1 = *(const vf4*)(xr1 + 64 + l16 * 4);
        float p0 = dot4(xa0, qa) + dot4(xb0, qb);
        float p1 = dot4(xa1, qa) + dot4(xb1, qb);
        p0 += __shfl_xor(p0, 1, 64);  p1 += __shfl_xor(p1, 1, 64);
        p0 += __shfl_xor(p0, 2, 64);  p1 += __shfl_xor(p1, 2, 64);
        p0 += __shfl_xor(p0, 4, 64);  p1 += __shfl_xor(p1, 4, 64);
        p0 += __shfl_xor(p0, 8, 64);  p1 += __shfl_xor(p1, 8, 64);
        UPD(m0, d0, ra0, rb0, p0, xa0, xb0)
        UPD(m1, d1, ra1, rb1, p1, xa1, xb1)
    }
    for (; base < e; base += 4) {  // tail: up to 7 rows in masked 4-row groups
        int row = base + quarter;
        const float* xr = x + (size_t)min(row, e - 1) * HDIM;
        vf4 xa = *(const vf4*)(xr + l16 * 4), xb = *(const vf4*)(xr + 64 + l16 * 4);
        float p = dot4(xa, qa) + dot4(xb, qb);
        p += __shfl_xor(p, 1, 64);
        p += __shfl_xor(p, 2, 64);
        p += __shfl_xor(p, 4, 64);
        p += __shfl_xor(p, 8, 64);
        if (row >= e) p = -1e30f;
        UPD(m0, d0, ra0, rb0, p, xa, xb)
    }
    {  // merge state1 -> state0
        float M = fmaxf(m0, m1);
        float w0 = __expf(m0 - M), w1 = __expf(m1 - M);
        d0 = d0 * w0 + d1 * w1;
        ra0 = ra0 * w0 + ra1 * w1;
        rb0 = rb0 * w0 + rb1 * w1;
        m0 = M;
    }
#pragma unroll
    for (int off = 16; off <= 32; off <<= 1) {  // merge the 4 quarter-states
        float om = __shfl_xor(m0, off, 64);
        float M = fmaxf(m0, om);
        float w = __expf(m0 - M);
        d0 *= w;
        ra0 *= w;
        rb0 *= w;
        d0 += __shfl_xor(d0, off, 64);
        ra0.x += __shfl_xor(ra0.x, off, 64);
        ra0.y += __shfl_xor(ra0.y, off, 64);
        ra0.z += __shfl_xor(ra0.z, off, 64);
        ra0.w += __shfl_xor(ra0.w, off, 64);
        rb0.x += __shfl_xor(rb0.x, off, 64);
        rb0.y += __shfl_xor(rb0.y, off, 64);
        rb0.z += __shfl_xor(rb0.z, off, 64);
        rb0.w += __shfl_xor(rb0.w, off, 64);
        m0 = M;
    }
    float inv = (d0 > 0.0f) ? 1.0f / d0 : 0.0f;
    float* dst = r_out + (size_t)seg * ldr + col_off;
    if (quarter == 0) {
        vf4 o = ra0 * inv;
        *(vf4*)(dst + l16 * 4) = o;
    } else if (quarter == 1) {
        vf4 o = rb0 * inv;
        *(vf4*)(dst + 64 + l16 * 4) = o;
    }
}

// ---- fused GEMM + LSTM cell. 128 rows x 128 gate-cols per block, 256 threads,
// 8x8 acc/thread (rows ty+16i, cols tx+16j). K-chunks of 32 -> LDS 2x17.4 KB.
// cols = { ct*32 + c + 128*gate : c in [0,32), gate in [0,4) }.
__global__ __launch_bounds__(256, 2) void k_gemm_lstm(const float* __restrict__ h_prev,
                                                      const float* __restrict__ r_prev,
                                                      const float* __restrict__ c_prev,
                                                      const float* __restrict__ Wc,
                                                      const float* __restrict__ b_ih,
                                                      const float* __restrict__ b_hh,
                                                      float* __restrict__ h_new,
                                                      float* __restrict__ c_new,
                                                      float* __restrict__ h_mirror) {
    __shared__ float As[128 * TS];
    __shared__ float Ws[128 * TS];
    int ct = blockIdx.y;            // hidx base ct*32
    int rb = blockIdx.x * 128;      // batch row base
    int tid = threadIdx.x;
    int tx = tid & 15, ty = tid >> 4;
    float acc[8][8];
#pragma unroll
    for (int i = 0; i < 8; ++i)
#pragma unroll
        for (int j = 0; j < 8; ++j) acc[i][j] = 0.0f;

    for (int kc = 0; kc < 8; ++kc) {  // K chunks of 32: kc 0..3 = h, 4..7 = r
        const float* src = (kc < 4) ? h_prev : r_prev;
        int kbase = (kc & 3) * 32;
#pragma unroll
        for (int i = 0; i < 4; ++i) {  // stage A: 128 rows x 32 k = 1024 vf4
            int li = tid + i * 256;
            int row = li >> 3;
            int c4 = (li & 7) * 4;
            *(vf4*)&As[row * TS + c4] = *(const vf4*)(src + (size_t)(rb + row) * HDIM + kbase + c4);
        }
#pragma unroll
        for (int i = 0; i < 4; ++i) {  // stage W: 128 cols x 32 k
            int li = tid + i * 256;
            int col = li >> 3;
            int c4 = (li & 7) * 4;
            int g = ct * 32 + (col & 31) + 128 * (col >> 5);
            *(vf4*)&Ws[col * TS + c4] = *(const vf4*)(Wc + (size_t)g * 256 + kc * 32 + c4);
        }
        __syncthreads();
#pragma unroll
        for (int k = 0; k < 32; k += 4) {
            vf4 a[8], b[8];
#pragma unroll
            for (int i = 0; i < 8; ++i) a[i] = *(vf4*)&As[(ty + 16 * i) * TS + k];
#pragma unroll
            for (int j = 0; j < 8; ++j) b[j] = *(vf4*)&Ws[(tx + 16 * j) * TS + k];
#pragma unroll
            for (int i = 0; i < 8; ++i)
#pragma unroll
                for (int j = 0; j < 8; ++j) {
                    acc[i][j] += a[i].x * b[j].x + a[i].y * b[j].y +
                                 a[i].z * b[j].z + a[i].w * b[j].w;
                }
        }
        __syncthreads();
    }
    // epilogue: thread (tx,ty): rows rb+ty+16i, hidx = ct*32 + tx + 16*jj,
    // gates: acc[i][jj + 2*gate] for gate = 0..3 (i,f,g,o)
#pragma unroll
    for (int jj = 0; jj < 2; ++jj) {
        int hidx = ct * 32 + tx + 16 * jj;
        float bi = b_ih[hidx] + b_hh[hidx];
        float bf = b_ih[HDIM + hidx] + b_hh[HDIM + hidx];
        float bg = b_ih[2 * HDIM + hidx] + b_hh[2 * HDIM + hidx];
        float bo = b_ih[3 * HDIM + hidx] + b_hh[3 * HDIM + hidx];
#pragma unroll
        for (int i = 0; i < 8; ++i) {
            int row = rb + ty + 16 * i;
            float gi = acc[i][jj + 0] + bi;
            float gf = acc[i][jj + 2] + bf;
            float gg = acc[i][jj + 4] + bg;
            float go = acc[i][jj + 6] + bo;
            float cp = c_prev[(size_t)row * HDIM + hidx];
            float cn = sigm(gf) * cp + sigm(gi) * ftanh(gg);
            float hn = sigm(go) * ftanh(cn);
            c_new[(size_t)row * HDIM + hidx] = cn;
            h_new[(size_t)row * HDIM + hidx] = hn;
            if (h_mirror) h_mirror[(size_t)row * 2 * HDIM + hidx] = hn;
        }
    }
}

extern "C" void kernel_launch(void* const* d_in, const int* in_sizes, int n_in,
                              void* d_out, int out_size, void* d_ws, size_t ws_size,
                              hipStream_t stream) {
    const float* x = (const float*)d_in[0];
    const int* batch_vec = (const int*)d_in[1];
    const float* W_ih = (const float*)d_in[2];
    const float* W_hh = (const float*)d_in[3];
    const float* b_ih = (const float*)d_in[4];
    const float* b_hh = (const float*)d_in[5];
    float* out = (float*)d_out;

    int N = in_sizes[1];
    int B = out_size / (2 * HDIM);

    char* ws = (char*)d_ws;
    float* Wc = (float*)ws;   ws += (size_t)G4 * 2 * HDIM * 4;
    float* h_a = (float*)ws;  ws += (size_t)B * HDIM * 4;
    float* h_b = (float*)ws;  ws += (size_t)B * HDIM * 4;
    float* cbuf = (float*)ws; ws += (size_t)B * HDIM * 4;
    float* rbuf = (float*)ws; ws += (size_t)B * HDIM * 4;
    int* seg = (int*)ws;      ws += (size_t)(B + 1) * 4;

    int setup_grid = (B * HDIM + 255) / 256;
    k_setup<<<setup_grid, 256, 0, stream>>>(W_ih, W_hh, b_ih, b_hh, batch_vec, N, B,
                                            Wc, seg, h_a, cbuf);

    dim3 ggrid(B / 128, 4);
    // serpentine: fwd, rev, fwd -> each pass starts where the previous left the L3
    k_attn<<<(B + 3) / 4, 256, 0, stream>>>(x, h_a, seg, rbuf, HDIM, 0, B, 0);
    k_gemm_lstm<<<ggrid, 256, 0, stream>>>(h_a, rbuf, cbuf, Wc, b_ih, b_hh, h_b, cbuf, nullptr);
    k_attn<<<(B + 3) / 4, 256, 0, stream>>>(x, h_b, seg, rbuf, HDIM, 0, B, 1);
    k_gemm_lstm<<<ggrid, 256, 0, stream>>>(h_b, rbuf, cbuf, Wc, b_ih, b_hh, h_a, cbuf, out);
    k_attn<<<(B + 3) / 4, 256, 0, stream>>>(x, h_a, seg, out, 2 * HDIM, HDIM, B, 0);
}

// Round 5
// 559.253 us; speedup vs baseline: 5.8942x; 5.8942x over previous
//
#include <hip/hip_runtime.h>
#include <math.h>

#define HDIM 128
#define G4 512  // 4*H
#define TS 36   // LDS row stride (floats): mult of 4 (aligned vf4); 36%32=4 -> 2-way banks max

typedef float vf4 __attribute__((ext_vector_type(4)));

__device__ __forceinline__ float sigm(float v) { return 1.0f / (1.0f + __expf(-v)); }
__device__ __forceinline__ float ftanh(float v) {
    return 1.0f - 2.0f / (__expf(2.0f * v) + 1.0f);
}
__device__ __forceinline__ float dot4(vf4 a, vf4 b) {
    return a.x * b.x + a.y * b.y + a.z * b.z + a.w * b.w;
}

// ---- fused setup: Wc prep + segment starts + step-0 LSTM (gates = bias)
__global__ __launch_bounds__(256) void k_setup(const float* __restrict__ W_ih,
                                               const float* __restrict__ W_hh,
                                               const float* __restrict__ b_ih,
                                               const float* __restrict__ b_hh,
                                               const int* __restrict__ batch_vec, int N, int B,
                                               float* __restrict__ Wc, int* __restrict__ seg_start,
                                               float* __restrict__ h, float* __restrict__ c) {
    int t = blockIdx.x * 256 + threadIdx.x;
    if (t < B * HDIM) {  // step-0 LSTM: h=c=0, gates = b_ih+b_hh
        int hid = t & (HDIM - 1);
        float gi = b_ih[hid] + b_hh[hid];
        float gg = b_ih[2 * HDIM + hid] + b_hh[2 * HDIM + hid];
        float go = b_ih[3 * HDIM + hid] + b_hh[3 * HDIM + hid];
        float cv = sigm(gi) * ftanh(gg);
        c[t] = cv;
        h[t] = sigm(go) * ftanh(cv);
    }
    if (t < G4 * 2 * HDIM) {  // Wc[512][256] = [W_ih[:,:128]+W_hh | W_ih[:,128:]]
        int g = t >> 8;
        int k = t & 255;
        float w = W_ih[g * 256 + k];
        if (k < HDIM) w += W_hh[g * HDIM + k];
        Wc[t] = w;
    }
    if (t <= B) {  // segment starts: lower_bound over sorted batch_vec
        int lo = 0, hi = N;
        while (lo < hi) {
            int mid = (lo + hi) >> 1;
            if (batch_vec[mid] < t) lo = mid + 1; else hi = mid;
        }
        seg_start[t] = lo;
    }
}

// ---- fused attention: one wave/segment, 16 lanes/row x 4 rows, dual online state.
#define UPD(m_, d_, ra_, rb_, p_, xa_, xb_)  \
    {                                        \
        float mn_ = fmaxf(m_, p_);           \
        float sc_ = __expf(m_ - mn_);        \
        float pe_ = __expf(p_ - mn_);        \
        d_ = d_ * sc_ + pe_;                 \
        ra_ = ra_ * sc_ + pe_ * xa_;         \
        rb_ = rb_ * sc_ + pe_ * xb_;         \
        m_ = mn_;                            \
    }

__global__ __launch_bounds__(256) void k_attn(const float* __restrict__ x,
                                              const float* __restrict__ q,
                                              const int* __restrict__ seg_start,
                                              float* __restrict__ r_out, int ldr, int col_off,
                                              int B, int rev) {
    int wave = threadIdx.x >> 6;
    int lane = threadIdx.x & 63;
    int l16 = lane & 15;
    int quarter = lane >> 4;
    int gid = (blockIdx.x << 2) + wave;
    if (gid >= B) return;
    int seg = rev ? (B - 1 - gid) : gid;
    int s = seg_start[seg];
    int e = seg_start[seg + 1];

    const float* qrow = q + (size_t)seg * HDIM;
    vf4 qa = *(const vf4*)(qrow + l16 * 4);
    vf4 qb = *(const vf4*)(qrow + 64 + l16 * 4);

    float m0 = 0.0f, d0 = 0.0f, m1 = 0.0f, d1 = 0.0f;
    vf4 ra0 = {0.f, 0.f, 0.f, 0.f}, rb0 = {0.f, 0.f, 0.f, 0.f};
    vf4 ra1 = {0.f, 0.f, 0.f, 0.f}, rb1 = {0.f, 0.f, 0.f, 0.f};

    int base = s;
#pragma unroll 2
    for (; base + 8 <= e; base += 8) {
        const float* xr0 = x + (size_t)(base + quarter) * HDIM;
        const float* xr1 = xr0 + 4 * HDIM;
        vf4 xa0 = *(const vf4*)(xr0 + l16 * 4), xb0 = *(const vf4*)(xr0 + 64 + l16 * 4);
        vf4 xa1 = *(const vf4*)(xr1 + l16 * 4), xb1 = *(const vf4*)(xr1 + 64 + l16 * 4);
        float p0 = dot4(xa0, qa) + dot4(xb0, qb);
        float p1 = dot4(xa1, qa) + dot4(xb1, qb);
        p0 += __shfl_xor(p0, 1, 64);  p1 += __shfl_xor(p1, 1, 64);
        p0 += __shfl_xor(p0, 2, 64);  p1 += __shfl_xor(p1, 2, 64);
        p0 += __shfl_xor(p0, 4, 64);  p1 += __shfl_xor(p1, 4, 64);
        p0 += __shfl_xor(p0, 8, 64);  p1 += __shfl_xor(p1, 8, 64);
        UPD(m0, d0, ra0, rb0, p0, xa0, xb0)
        UPD(m1, d1, ra1, rb1, p1, xa1, xb1)
    }
    for (; base < e; base += 4) {  // tail: up to 7 rows in masked 4-row groups
        int row = base + quarter;
        const float* xr = x + (size_t)min(row, e - 1) * HDIM;
        vf4 xa = *(const vf4*)(xr + l16 * 4), xb = *(const vf4*)(xr + 64 + l16 * 4);
        float p = dot4(xa, qa) + dot4(xb, qb);
        p += __shfl_xor(p, 1, 64);
        p += __shfl_xor(p, 2, 64);
        p += __shfl_xor(p, 4, 64);
        p += __shfl_xor(p, 8, 64);
        if (row >= e) p = -1e30f;
        UPD(m0, d0, ra0, rb0, p, xa, xb)
    }
    {  // merge state1 -> state0
        float M = fmaxf(m0, m1);
        float w0 = __expf(m0 - M), w1 = __expf(m1 - M);
        d0 = d0 * w0 + d1 * w1;
        ra0 = ra0 * w0 + ra1 * w1;
        rb0 = rb0 * w0 + rb1 * w1;
        m0 = M;
    }
#pragma unroll
    for (int off = 16; off <= 32; off <<= 1) {  // merge the 4 quarter-states
        float om = __shfl_xor(m0, off, 64);
        float M = fmaxf(m0, om);
        float w = __expf(m0 - M);
        d0 *= w;
        ra0 *= w;
        rb0 *= w;
        d0 += __shfl_xor(d0, off, 64);
        ra0.x += __shfl_xor(ra0.x, off, 64);
        ra0.y += __shfl_xor(ra0.y, off, 64);
        ra0.z += __shfl_xor(ra0.z, off, 64);
        ra0.w += __shfl_xor(ra0.w, off, 64);
        rb0.x += __shfl_xor(rb0.x, off, 64);
        rb0.y += __shfl_xor(rb0.y, off, 64);
        rb0.z += __shfl_xor(rb0.z, off, 64);
        rb0.w += __shfl_xor(rb0.w, off, 64);
        m0 = M;
    }
    float inv = (d0 > 0.0f) ? 1.0f / d0 : 0.0f;
    float* dst = r_out + (size_t)seg * ldr + col_off;
    if (quarter == 0) {
        vf4 o = ra0 * inv;
        *(vf4*)(dst + l16 * 4) = o;
    } else if (quarter == 1) {
        vf4 o = rb0 * inv;
        *(vf4*)(dst + 64 + l16 * 4) = o;
    }
}

// ---- fused GEMM + LSTM cell. 128 rows x 64 gate-cols per block, 256 threads,
// 8x4 acc/thread (rows ty+16i, col tx -> hidx ct*16+tx, 4 gates). K-chunks of 32.
// cols = { ct*16 + c + 128*gate : c in [0,16), gate in [0,4) }.
// Regs: 32 acc + 32 a + 16 b ~= 110 total -> no spill. LDS 27.6 KB -> 4 blocks/CU;
// grid (128, 8) = exactly 4 blocks/CU, one clean round.
__global__ __launch_bounds__(256) void k_gemm_lstm(const float* __restrict__ h_prev,
                                                   const float* __restrict__ r_prev,
                                                   const float* __restrict__ c_prev,
                                                   const float* __restrict__ Wc,
                                                   const float* __restrict__ b_ih,
                                                   const float* __restrict__ b_hh,
                                                   float* __restrict__ h_new,
                                                   float* __restrict__ c_new,
                                                   float* __restrict__ h_mirror) {
    __shared__ float As[128 * TS];
    __shared__ float Ws[64 * TS];
    int ct = blockIdx.y;            // hidx base ct*16
    int rb = blockIdx.x * 128;      // batch row base
    int tid = threadIdx.x;
    int tx = tid & 15, ty = tid >> 4;   // ty in [0,16)
    float acc[8][4];
#pragma unroll
    for (int i = 0; i < 8; ++i)
#pragma unroll
        for (int j = 0; j < 4; ++j) acc[i][j] = 0.0f;

    for (int kc = 0; kc < 8; ++kc) {  // K chunks of 32: kc 0..3 = h, 4..7 = r
        const float* src = (kc < 4) ? h_prev : r_prev;
        int kbase = (kc & 3) * 32;
#pragma unroll
        for (int i = 0; i < 4; ++i) {  // stage A: 128 rows x 32 k = 1024 vf4
            int li = tid + i * 256;
            int row = li >> 3;
            int c4 = (li & 7) * 4;
            *(vf4*)&As[row * TS + c4] = *(const vf4*)(src + (size_t)(rb + row) * HDIM + kbase + c4);
        }
#pragma unroll
        for (int i = 0; i < 2; ++i) {  // stage W: 64 cols x 32 k = 512 vf4
            int li = tid + i * 256;
            int col = li >> 3;
            int c4 = (li & 7) * 4;
            int g = ct * 16 + (col & 15) + 128 * (col >> 4);
            *(vf4*)&Ws[col * TS + c4] = *(const vf4*)(Wc + (size_t)g * 256 + kc * 32 + c4);
        }
        __syncthreads();
#pragma unroll
        for (int k = 0; k < 32; k += 4) {
            vf4 a[8], b[4];
#pragma unroll
            for (int i = 0; i < 8; ++i) a[i] = *(vf4*)&As[(ty + 16 * i) * TS + k];
#pragma unroll
            for (int j = 0; j < 4; ++j) b[j] = *(vf4*)&Ws[(tx + 16 * j) * TS + k];
#pragma unroll
            for (int i = 0; i < 8; ++i)
#pragma unroll
                for (int j = 0; j < 4; ++j) {
                    acc[i][j] += a[i].x * b[j].x + a[i].y * b[j].y +
                                 a[i].z * b[j].z + a[i].w * b[j].w;
                }
        }
        __syncthreads();
    }
    // epilogue: thread (tx,ty) owns hidx = ct*16+tx, rows rb+ty+16i, gates j (i,f,g,o)
    int hidx = ct * 16 + tx;
    float bi = b_ih[hidx] + b_hh[hidx];
    float bf = b_ih[HDIM + hidx] + b_hh[HDIM + hidx];
    float bg = b_ih[2 * HDIM + hidx] + b_hh[2 * HDIM + hidx];
    float bo = b_ih[3 * HDIM + hidx] + b_hh[3 * HDIM + hidx];
#pragma unroll
    for (int i = 0; i < 8; ++i) {
        int row = rb + ty + 16 * i;
        float gi = acc[i][0] + bi;
        float gf = acc[i][1] + bf;
        float gg = acc[i][2] + bg;
        float go = acc[i][3] + bo;
        float cp = c_prev[(size_t)row * HDIM + hidx];
        float cn = sigm(gf) * cp + sigm(gi) * ftanh(gg);
        float hn = sigm(go) * ftanh(cn);
        c_new[(size_t)row * HDIM + hidx] = cn;
        h_new[(size_t)row * HDIM + hidx] = hn;
        if (h_mirror) h_mirror[(size_t)row * 2 * HDIM + hidx] = hn;
    }
}

extern "C" void kernel_launch(void* const* d_in, const int* in_sizes, int n_in,
                              void* d_out, int out_size, void* d_ws, size_t ws_size,
                              hipStream_t stream) {
    const float* x = (const float*)d_in[0];
    const int* batch_vec = (const int*)d_in[1];
    const float* W_ih = (const float*)d_in[2];
    const float* W_hh = (const float*)d_in[3];
    const float* b_ih = (const float*)d_in[4];
    const float* b_hh = (const float*)d_in[5];
    float* out = (float*)d_out;

    int N = in_sizes[1];
    int B = out_size / (2 * HDIM);

    char* ws = (char*)d_ws;
    float* Wc = (float*)ws;   ws += (size_t)G4 * 2 * HDIM * 4;
    float* h_a = (float*)ws;  ws += (size_t)B * HDIM * 4;
    float* h_b = (float*)ws;  ws += (size_t)B * HDIM * 4;
    float* cbuf = (float*)ws; ws += (size_t)B * HDIM * 4;
    float* rbuf = (float*)ws; ws += (size_t)B * HDIM * 4;
    int* seg = (int*)ws;      ws += (size_t)(B + 1) * 4;

    int setup_grid = (B * HDIM + 255) / 256;
    k_setup<<<setup_grid, 256, 0, stream>>>(W_ih, W_hh, b_ih, b_hh, batch_vec, N, B,
                                            Wc, seg, h_a, cbuf);

    dim3 ggrid(B / 128, 8);
    // serpentine: fwd, rev, fwd -> each pass starts where the previous left the L3
    k_attn<<<(B + 3) / 4, 256, 0, stream>>>(x, h_a, seg, rbuf, HDIM, 0, B, 0);
    k_gemm_lstm<<<ggrid, 256, 0, stream>>>(h_a, rbuf, cbuf, Wc, b_ih, b_hh, h_b, cbuf, nullptr);
    k_attn<<<(B + 3) / 4, 256, 0, stream>>>(x, h_b, seg, rbuf, HDIM, 0, B, 1);
    k_gemm_lstm<<<ggrid, 256, 0, stream>>>(h_b, rbuf, cbuf, Wc, b_ih, b_hh, h_a, cbuf, out);
    k_attn<<<(B + 3) / 4, 256, 0, stream>>>(x, h_a, seg, out, 2 * HDIM, HDIM, B, 0);
}

// Round 6
// 487.697 us; speedup vs baseline: 6.7590x; 1.1467x over previous
//
#include <hip/hip_runtime.h>
#include <math.h>

#define HDIM 128
#define G4 512  // 4*H
#define TS 36   // GEMM LDS row stride (floats)

typedef float vf4 __attribute__((ext_vector_type(4)));
typedef unsigned short u16x8 __attribute__((ext_vector_type(8)));

__device__ __forceinline__ float sigm(float v) { return 1.0f / (1.0f + __expf(-v)); }
__device__ __forceinline__ float ftanh(float v) {
    return 1.0f - 2.0f / (__expf(2.0f * v) + 1.0f);
}
__device__ __forceinline__ float dot4(vf4 a, vf4 b) {
    return a.x * b.x + a.y * b.y + a.z * b.z + a.w * b.w;
}
__device__ __forceinline__ vf4 ldnt4(const float* p) {
    return __builtin_nontemporal_load((const vf4*)p);
}
__device__ __forceinline__ unsigned short f2bf(float f) {  // RTNE
    unsigned u = __float_as_uint(f);
    u += 0x7fff + ((u >> 16) & 1);
    return (unsigned short)(u >> 16);
}
__device__ __forceinline__ float bf2f(unsigned short h) {
    return __uint_as_float(((unsigned)h) << 16);
}

// ---- fused setup: Wc prep + segment starts + step-0 LSTM (gates = bias)
__global__ __launch_bounds__(256) void k_setup(const float* __restrict__ W_ih,
                                               const float* __restrict__ W_hh,
                                               const float* __restrict__ b_ih,
                                               const float* __restrict__ b_hh,
                                               const int* __restrict__ batch_vec, int N, int B,
                                               float* __restrict__ Wc, int* __restrict__ seg_start,
                                               float* __restrict__ h, float* __restrict__ c) {
    int t = blockIdx.x * 256 + threadIdx.x;
    if (t < B * HDIM) {
        int hid = t & (HDIM - 1);
        float gi = b_ih[hid] + b_hh[hid];
        float gg = b_ih[2 * HDIM + hid] + b_hh[2 * HDIM + hid];
        float go = b_ih[3 * HDIM + hid] + b_hh[3 * HDIM + hid];
        float cv = sigm(gi) * ftanh(gg);
        c[t] = cv;
        h[t] = sigm(go) * ftanh(cv);
    }
    if (t < G4 * 2 * HDIM) {
        int g = t >> 8;
        int k = t & 255;
        float w = W_ih[g * 256 + k];
        if (k < HDIM) w += W_hh[g * HDIM + k];
        Wc[t] = w;
    }
    if (t <= B) {
        int lo = 0, hi = N;
        while (lo < hi) {
            int mid = (lo + hi) >> 1;
            if (batch_vec[mid] < t) lo = mid + 1; else hi = mid;
        }
        seg_start[t] = lo;
    }
}

#define UPD(m_, d_, ra_, rb_, p_, xa_, xb_)  \
    {                                        \
        float mn_ = fmaxf(m_, p_);           \
        float sc_ = __expf(m_ - mn_);        \
        float pe_ = __expf(p_ - mn_);        \
        d_ = d_ * sc_ + pe_;                 \
        ra_ = ra_ * sc_ + pe_ * xa_;         \
        rb_ = rb_ * sc_ + pe_ * xb_;         \
        m_ = mn_;                            \
    }

#define MERGE_AND_WRITE()                                                     \
    {                                                                         \
        float M = fmaxf(m0, m1);                                              \
        float w0 = __expf(m0 - M), w1 = __expf(m1 - M);                       \
        d0 = d0 * w0 + d1 * w1;                                               \
        ra0 = ra0 * w0 + ra1 * w1;                                            \
        rb0 = rb0 * w0 + rb1 * w1;                                            \
        m0 = M;                                                               \
    }                                                                         \
    _Pragma("unroll")                                                         \
    for (int off = 16; off <= 32; off <<= 1) {                                \
        float om = __shfl_xor(m0, off, 64);                                   \
        float M = fmaxf(m0, om);                                              \
        float w = __expf(m0 - M);                                             \
        d0 *= w; ra0 *= w; rb0 *= w;                                          \
        d0 += __shfl_xor(d0, off, 64);                                        \
        ra0.x += __shfl_xor(ra0.x, off, 64);                                  \
        ra0.y += __shfl_xor(ra0.y, off, 64);                                  \
        ra0.z += __shfl_xor(ra0.z, off, 64);                                  \
        ra0.w += __shfl_xor(ra0.w, off, 64);                                  \
        rb0.x += __shfl_xor(rb0.x, off, 64);                                  \
        rb0.y += __shfl_xor(rb0.y, off, 64);                                  \
        rb0.z += __shfl_xor(rb0.z, off, 64);                                  \
        rb0.w += __shfl_xor(rb0.w, off, 64);                                  \
        m0 = M;                                                               \
    }                                                                         \
    float inv = (d0 > 0.0f) ? 1.0f / d0 : 0.0f;                               \
    if (quarter == 0) {                                                       \
        float* dst = r_out + (size_t)seg * ldr + col_off + l16 * 8;           \
        *(vf4*)dst = ra0 * inv;                                               \
        *(vf4*)(dst + 4) = rb0 * inv;                                         \
    }

// ---- pass 1: fp32 x attention + fused bf16 conversion of x. Lane owns cols [l16*8, l16*8+8).
__global__ __launch_bounds__(256) void k_attn_cvt(const float* __restrict__ x,
                                                  unsigned short* __restrict__ x16,
                                                  const float* __restrict__ q,
                                                  const int* __restrict__ seg_start,
                                                  float* __restrict__ r_out, int B) {
    const int ldr = HDIM, col_off = 0;
    int wave = threadIdx.x >> 6;
    int lane = threadIdx.x & 63;
    int l16 = lane & 15;
    int quarter = lane >> 4;
    int seg = (blockIdx.x << 2) + wave;
    if (seg >= B) return;
    int s = seg_start[seg], e = seg_start[seg + 1];

    const float* qrow = q + (size_t)seg * HDIM + l16 * 8;
    vf4 qa = *(const vf4*)qrow;
    vf4 qb = *(const vf4*)(qrow + 4);

    float m0 = 0.0f, d0 = 0.0f, m1 = 0.0f, d1 = 0.0f;
    vf4 ra0 = {0.f, 0.f, 0.f, 0.f}, rb0 = {0.f, 0.f, 0.f, 0.f};
    vf4 ra1 = {0.f, 0.f, 0.f, 0.f}, rb1 = {0.f, 0.f, 0.f, 0.f};

    int base = s;
#pragma unroll 2
    for (; base + 8 <= e; base += 8) {
        const float* xr0 = x + (size_t)(base + quarter) * HDIM + l16 * 8;
        const float* xr1 = xr0 + 4 * HDIM;
        vf4 xa0 = ldnt4(xr0), xb0 = ldnt4(xr0 + 4);
        vf4 xa1 = ldnt4(xr1), xb1 = ldnt4(xr1 + 4);
        u16x8 c0, c1;
        c0[0] = f2bf(xa0.x); c0[1] = f2bf(xa0.y); c0[2] = f2bf(xa0.z); c0[3] = f2bf(xa0.w);
        c0[4] = f2bf(xb0.x); c0[5] = f2bf(xb0.y); c0[6] = f2bf(xb0.z); c0[7] = f2bf(xb0.w);
        c1[0] = f2bf(xa1.x); c1[1] = f2bf(xa1.y); c1[2] = f2bf(xa1.z); c1[3] = f2bf(xa1.w);
        c1[4] = f2bf(xb1.x); c1[5] = f2bf(xb1.y); c1[6] = f2bf(xb1.z); c1[7] = f2bf(xb1.w);
        *(u16x8*)(x16 + (size_t)(base + quarter) * HDIM + l16 * 8) = c0;
        *(u16x8*)(x16 + (size_t)(base + 4 + quarter) * HDIM + l16 * 8) = c1;
        float p0 = dot4(xa0, qa) + dot4(xb0, qb);
        float p1 = dot4(xa1, qa) + dot4(xb1, qb);
        p0 += __shfl_xor(p0, 1, 64);  p1 += __shfl_xor(p1, 1, 64);
        p0 += __shfl_xor(p0, 2, 64);  p1 += __shfl_xor(p1, 2, 64);
        p0 += __shfl_xor(p0, 4, 64);  p1 += __shfl_xor(p1, 4, 64);
        p0 += __shfl_xor(p0, 8, 64);  p1 += __shfl_xor(p1, 8, 64);
        UPD(m0, d0, ra0, rb0, p0, xa0, xb0)
        UPD(m1, d1, ra1, rb1, p1, xa1, xb1)
    }
    for (; base < e; base += 4) {
        int row = base + quarter;
        const float* xr = x + (size_t)min(row, e - 1) * HDIM + l16 * 8;
        vf4 xa = ldnt4(xr), xb = ldnt4(xr + 4);
        u16x8 c0;
        c0[0] = f2bf(xa.x); c0[1] = f2bf(xa.y); c0[2] = f2bf(xa.z); c0[3] = f2bf(xa.w);
        c0[4] = f2bf(xb.x); c0[5] = f2bf(xb.y); c0[6] = f2bf(xb.z); c0[7] = f2bf(xb.w);
        *(u16x8*)(x16 + (size_t)min(row, e - 1) * HDIM + l16 * 8) = c0;
        float p = dot4(xa, qa) + dot4(xb, qb);
        p += __shfl_xor(p, 1, 64);
        p += __shfl_xor(p, 2, 64);
        p += __shfl_xor(p, 4, 64);
        p += __shfl_xor(p, 8, 64);
        if (row >= e) p = -1e30f;
        UPD(m0, d0, ra0, rb0, p, xa, xb)
    }
    MERGE_AND_WRITE()
}

// ---- passes 2,3: bf16 x attention. rev=1 walks segments back-to-front (serpentine).
__global__ __launch_bounds__(256) void k_attn_b16(const unsigned short* __restrict__ x16,
                                                  const float* __restrict__ q,
                                                  const int* __restrict__ seg_start,
                                                  float* __restrict__ r_out, int ldr, int col_off,
                                                  int B, int rev) {
    int wave = threadIdx.x >> 6;
    int lane = threadIdx.x & 63;
    int l16 = lane & 15;
    int quarter = lane >> 4;
    int gid = (blockIdx.x << 2) + wave;
    if (gid >= B) return;
    int seg = rev ? (B - 1 - gid) : gid;
    int s = seg_start[seg], e = seg_start[seg + 1];

    const float* qrow = q + (size_t)seg * HDIM + l16 * 8;
    vf4 qa = *(const vf4*)qrow;
    vf4 qb = *(const vf4*)(qrow + 4);

    float m0 = 0.0f, d0 = 0.0f, m1 = 0.0f, d1 = 0.0f;
    vf4 ra0 = {0.f, 0.f, 0.f, 0.f}, rb0 = {0.f, 0.f, 0.f, 0.f};
    vf4 ra1 = {0.f, 0.f, 0.f, 0.f}, rb1 = {0.f, 0.f, 0.f, 0.f};

    int base = s;
#pragma unroll 2
    for (; base + 8 <= e; base += 8) {
        const unsigned short* xr0 = x16 + (size_t)(base + quarter) * HDIM + l16 * 8;
        u16x8 u0 = *(const u16x8*)xr0;
        u16x8 u1 = *(const u16x8*)(xr0 + 4 * HDIM);
        vf4 xa0 = {bf2f(u0[0]), bf2f(u0[1]), bf2f(u0[2]), bf2f(u0[3])};
        vf4 xb0 = {bf2f(u0[4]), bf2f(u0[5]), bf2f(u0[6]), bf2f(u0[7])};
        vf4 xa1 = {bf2f(u1[0]), bf2f(u1[1]), bf2f(u1[2]), bf2f(u1[3])};
        vf4 xb1 = {bf2f(u1[4]), bf2f(u1[5]), bf2f(u1[6]), bf2f(u1[7])};
        float p0 = dot4(xa0, qa) + dot4(xb0, qb);
        float p1 = dot4(xa1, qa) + dot4(xb1, qb);
        p0 += __shfl_xor(p0, 1, 64);  p1 += __shfl_xor(p1, 1, 64);
        p0 += __shfl_xor(p0, 2, 64);  p1 += __shfl_xor(p1, 2, 64);
        p0 += __shfl_xor(p0, 4, 64);  p1 += __shfl_xor(p1, 4, 64);
        p0 += __shfl_xor(p0, 8, 64);  p1 += __shfl_xor(p1, 8, 64);
        UPD(m0, d0, ra0, rb0, p0, xa0, xb0)
        UPD(m1, d1, ra1, rb1, p1, xa1, xb1)
    }
    for (; base < e; base += 4) {
        int row = base + quarter;
        const unsigned short* xr = x16 + (size_t)min(row, e - 1) * HDIM + l16 * 8;
        u16x8 u0 = *(const u16x8*)xr;
        vf4 xa = {bf2f(u0[0]), bf2f(u0[1]), bf2f(u0[2]), bf2f(u0[3])};
        vf4 xb = {bf2f(u0[4]), bf2f(u0[5]), bf2f(u0[6]), bf2f(u0[7])};
        float p = dot4(xa, qa) + dot4(xb, qb);
        p += __shfl_xor(p, 1, 64);
        p += __shfl_xor(p, 2, 64);
        p += __shfl_xor(p, 4, 64);
        p += __shfl_xor(p, 8, 64);
        if (row >= e) p = -1e30f;
        UPD(m0, d0, ra0, rb0, p, xa, xb)
    }
    MERGE_AND_WRITE()
}

// ---- fused GEMM + LSTM cell (unchanged from R5: 128x64 tile, 8x4 acc, no spill).
__global__ __launch_bounds__(256) void k_gemm_lstm(const float* __restrict__ h_prev,
                                                   const float* __restrict__ r_prev,
                                                   const float* __restrict__ c_prev,
                                                   const float* __restrict__ Wc,
                                                   const float* __restrict__ b_ih,
                                                   const float* __restrict__ b_hh,
                                                   float* __restrict__ h_new,
                                                   float* __restrict__ c_new,
                                                   float* __restrict__ h_mirror) {
    __shared__ float As[128 * TS];
    __shared__ float Ws[64 * TS];
    int ct = blockIdx.y;
    int rb = blockIdx.x * 128;
    int tid = threadIdx.x;
    int tx = tid & 15, ty = tid >> 4;
    float acc[8][4];
#pragma unroll
    for (int i = 0; i < 8; ++i)
#pragma unroll
        for (int j = 0; j < 4; ++j) acc[i][j] = 0.0f;

    for (int kc = 0; kc < 8; ++kc) {
        const float* src = (kc < 4) ? h_prev : r_prev;
        int kbase = (kc & 3) * 32;
#pragma unroll
        for (int i = 0; i < 4; ++i) {
            int li = tid + i * 256;
            int row = li >> 3;
            int c4 = (li & 7) * 4;
            *(vf4*)&As[row * TS + c4] = *(const vf4*)(src + (size_t)(rb + row) * HDIM + kbase + c4);
        }
#pragma unroll
        for (int i = 0; i < 2; ++i) {
            int li = tid + i * 256;
            int col = li >> 3;
            int c4 = (li & 7) * 4;
            int g = ct * 16 + (col & 15) + 128 * (col >> 4);
            *(vf4*)&Ws[col * TS + c4] = *(const vf4*)(Wc + (size_t)g * 256 + kc * 32 + c4);
        }
        __syncthreads();
#pragma unroll
        for (int k = 0; k < 32; k += 4) {
            vf4 a[8], b[4];
#pragma unroll
            for (int i = 0; i < 8; ++i) a[i] = *(vf4*)&As[(ty + 16 * i) * TS + k];
#pragma unroll
            for (int j = 0; j < 4; ++j) b[j] = *(vf4*)&Ws[(tx + 16 * j) * TS + k];
#pragma unroll
            for (int i = 0; i < 8; ++i)
#pragma unroll
                for (int j = 0; j < 4; ++j) {
                    acc[i][j] += a[i].x * b[j].x + a[i].y * b[j].y +
                                 a[i].z * b[j].z + a[i].w * b[j].w;
                }
        }
        __syncthreads();
    }
    int hidx = ct * 16 + tx;
    float bi = b_ih[hidx] + b_hh[hidx];
    float bf = b_ih[HDIM + hidx] + b_hh[HDIM + hidx];
    float bg = b_ih[2 * HDIM + hidx] + b_hh[2 * HDIM + hidx];
    float bo = b_ih[3 * HDIM + hidx] + b_hh[3 * HDIM + hidx];
#pragma unroll
    for (int i = 0; i < 8; ++i) {
        int row = rb + ty + 16 * i;
        float gi = acc[i][0] + bi;
        float gf = acc[i][1] + bf;
        float gg = acc[i][2] + bg;
        float go = acc[i][3] + bo;
        float cp = c_prev[(size_t)row * HDIM + hidx];
        float cn = sigm(gf) * cp + sigm(gi) * ftanh(gg);
        float hn = sigm(go) * ftanh(cn);
        c_new[(size_t)row * HDIM + hidx] = cn;
        h_new[(size_t)row * HDIM + hidx] = hn;
        if (h_mirror) h_mirror[(size_t)row * 2 * HDIM + hidx] = hn;
    }
}

extern "C" void kernel_launch(void* const* d_in, const int* in_sizes, int n_in,
                              void* d_out, int out_size, void* d_ws, size_t ws_size,
                              hipStream_t stream) {
    const float* x = (const float*)d_in[0];
    const int* batch_vec = (const int*)d_in[1];
    const float* W_ih = (const float*)d_in[2];
    const float* W_hh = (const float*)d_in[3];
    const float* b_ih = (const float*)d_in[4];
    const float* b_hh = (const float*)d_in[5];
    float* out = (float*)d_out;

    int N = in_sizes[1];
    int B = out_size / (2 * HDIM);

    char* ws = (char*)d_ws;
    float* Wc = (float*)ws;            ws += (size_t)G4 * 2 * HDIM * 4;
    float* h_a = (float*)ws;           ws += (size_t)B * HDIM * 4;
    float* h_b = (float*)ws;           ws += (size_t)B * HDIM * 4;
    float* cbuf = (float*)ws;          ws += (size_t)B * HDIM * 4;
    float* rbuf = (float*)ws;          ws += (size_t)B * HDIM * 4;
    int* seg = (int*)ws;               ws += (size_t)(B + 1) * 4;
    ws = (char*)(((size_t)ws + 255) & ~(size_t)255);
    unsigned short* x16 = (unsigned short*)ws;  // N*128*2 = 256 MB

    int setup_grid = (B * HDIM + 255) / 256;
    k_setup<<<setup_grid, 256, 0, stream>>>(W_ih, W_hh, b_ih, b_hh, batch_vec, N, B,
                                            Wc, seg, h_a, cbuf);

    dim3 ggrid(B / 128, 8);
    // pass 1: fp32 + fused bf16 conversion (fwd). passes 2,3: bf16, serpentine rev/fwd.
    k_attn_cvt<<<(B + 3) / 4, 256, 0, stream>>>(x, x16, h_a, seg, rbuf, B);
    k_gemm_lstm<<<ggrid, 256, 0, stream>>>(h_a, rbuf, cbuf, Wc, b_ih, b_hh, h_b, cbuf, nullptr);
    k_attn_b16<<<(B + 3) / 4, 256, 0, stream>>>(x16, h_b, seg, rbuf, HDIM, 0, B, 1);
    k_gemm_lstm<<<ggrid, 256, 0, stream>>>(h_b, rbuf, cbuf, Wc, b_ih, b_hh, h_a, cbuf, out);
    k_attn_b16<<<(B + 3) / 4, 256, 0, stream>>>(x16, h_a, seg, out, 2 * HDIM, HDIM, B, 0);
}

// Round 7
// 478.870 us; speedup vs baseline: 6.8836x; 1.0184x over previous
//
#include <hip/hip_runtime.h>
#include <math.h>

#define HDIM 128
#define G4 512  // 4*H
#define TS 36   // GEMM LDS row stride (floats)

typedef float vf4 __attribute__((ext_vector_type(4)));
typedef unsigned short u16x8 __attribute__((ext_vector_type(8)));

__device__ __forceinline__ float sigm(float v) { return 1.0f / (1.0f + __expf(-v)); }
__device__ __forceinline__ float ftanh(float v) {
    return 1.0f - 2.0f / (__expf(2.0f * v) + 1.0f);
}
__device__ __forceinline__ float dot4(vf4 a, vf4 b) {
    return a.x * b.x + a.y * b.y + a.z * b.z + a.w * b.w;
}
__device__ __forceinline__ vf4 ldnt4(const float* p) {
    return __builtin_nontemporal_load((const vf4*)p);
}
__device__ __forceinline__ unsigned short f2bf(float f) {  // RTNE
    unsigned u = __float_as_uint(f);
    u += 0x7fff + ((u >> 16) & 1);
    return (unsigned short)(u >> 16);
}
__device__ __forceinline__ float bf2f(unsigned short h) {
    return __uint_as_float(((unsigned)h) << 16);
}

// ---- setup: Wc prep + segment starts (no B*H work any more)
__global__ __launch_bounds__(256) void k_setup(const float* __restrict__ W_ih,
                                               const float* __restrict__ W_hh,
                                               const int* __restrict__ batch_vec, int N, int B,
                                               float* __restrict__ Wc, int* __restrict__ seg_start) {
    int t = blockIdx.x * 256 + threadIdx.x;
    if (t < G4 * 2 * HDIM) {  // Wc[512][256] = [W_ih[:,:128]+W_hh | W_ih[:,128:]]
        int g = t >> 8;
        int k = t & 255;
        float w = W_ih[g * 256 + k];
        if (k < HDIM) w += W_hh[g * HDIM + k];
        Wc[t] = w;
    }
    if (t <= B) {  // lower_bound over sorted batch_vec
        int lo = 0, hi = N;
        while (lo < hi) {
            int mid = (lo + hi) >> 1;
            if (batch_vec[mid] < t) lo = mid + 1; else hi = mid;
        }
        seg_start[t] = lo;
    }
}

// ---- gh0[g] = sum_k Wc[g][k] * h0[k]  (k < 128), h0 = step-0 hidden (same for all graphs)
__global__ __launch_bounds__(256) void k_head(const float* __restrict__ Wc,
                                              const float* __restrict__ b_ih,
                                              const float* __restrict__ b_hh,
                                              float* __restrict__ gh0) {
    __shared__ float h0s[HDIM];
    int t = threadIdx.x;
    int g = blockIdx.x * 256 + t;
    if (t < HDIM) {
        float bi = b_ih[t] + b_hh[t];
        float bg = b_ih[2 * HDIM + t] + b_hh[2 * HDIM + t];
        float bo = b_ih[3 * HDIM + t] + b_hh[3 * HDIM + t];
        float c0 = sigm(bi) * ftanh(bg);
        h0s[t] = sigm(bo) * ftanh(c0);
    }
    __syncthreads();
    float s = 0.0f;
#pragma unroll
    for (int k = 0; k < HDIM; k += 4) {
        vf4 w = *(const vf4*)(Wc + (size_t)g * 256 + k);
        s += w.x * h0s[k] + w.y * h0s[k + 1] + w.z * h0s[k + 2] + w.w * h0s[k + 3];
    }
    gh0[g] = s;
}

#define UPD(m_, d_, ra_, rb_, p_, xa_, xb_)  \
    {                                        \
        float mn_ = fmaxf(m_, p_);           \
        float sc_ = __expf(m_ - mn_);        \
        float pe_ = __expf(p_ - mn_);        \
        d_ = d_ * sc_ + pe_;                 \
        ra_ = ra_ * sc_ + pe_ * xa_;         \
        rb_ = rb_ * sc_ + pe_ * xb_;         \
        m_ = mn_;                            \
    }

#define SHFL16(p_)                  \
    p_ += __shfl_xor(p_, 1, 64);    \
    p_ += __shfl_xor(p_, 2, 64);    \
    p_ += __shfl_xor(p_, 4, 64);    \
    p_ += __shfl_xor(p_, 8, 64);

#define MERGE_AND_WRITE()                                                     \
    {                                                                         \
        float M = fmaxf(m0, m1);                                              \
        float w0 = __expf(m0 - M), w1 = __expf(m1 - M);                       \
        d0 = d0 * w0 + d1 * w1;                                               \
        ra0 = ra0 * w0 + ra1 * w1;                                            \
        rb0 = rb0 * w0 + rb1 * w1;                                            \
        m0 = M;                                                               \
    }                                                                         \
    _Pragma("unroll")                                                         \
    for (int off = 16; off <= 32; off <<= 1) {                                \
        float om = __shfl_xor(m0, off, 64);                                   \
        float M = fmaxf(m0, om);                                              \
        float w = __expf(m0 - M);                                             \
        d0 *= w; ra0 *= w; rb0 *= w;                                          \
        d0 += __shfl_xor(d0, off, 64);                                        \
        ra0.x += __shfl_xor(ra0.x, off, 64);                                  \
        ra0.y += __shfl_xor(ra0.y, off, 64);                                  \
        ra0.z += __shfl_xor(ra0.z, off, 64);                                  \
        ra0.w += __shfl_xor(ra0.w, off, 64);                                  \
        rb0.x += __shfl_xor(rb0.x, off, 64);                                  \
        rb0.y += __shfl_xor(rb0.y, off, 64);                                  \
        rb0.z += __shfl_xor(rb0.z, off, 64);                                  \
        rb0.w += __shfl_xor(rb0.w, off, 64);                                  \
        m0 = M;                                                               \
    }                                                                         \
    float inv = (d0 > 0.0f) ? 1.0f / d0 : 0.0f;                               \
    if (quarter == 0) {                                                       \
        float* dst = r_out + (size_t)seg * ldr + col_off + l16 * 8;           \
        *(vf4*)dst = ra0 * inv;                                               \
        *(vf4*)(dst + 4) = rb0 * inv;                                         \
    }

// ---- pass 1: fp32 x attention + fused bf16 conversion. q = q0 (identical for
// all graphs after step 0) computed in-register from biases. 16-row main loop.
__global__ __launch_bounds__(256) void k_attn_cvt(const float* __restrict__ x,
                                                  unsigned short* __restrict__ x16,
                                                  const float* __restrict__ b_ih,
                                                  const float* __restrict__ b_hh,
                                                  const int* __restrict__ seg_start,
                                                  float* __restrict__ r_out, int B) {
    const int ldr = HDIM, col_off = 0;
    int wave = threadIdx.x >> 6;
    int lane = threadIdx.x & 63;
    int l16 = lane & 15;
    int quarter = lane >> 4;
    int seg = (blockIdx.x << 2) + wave;
    if (seg >= B) return;
    int s = seg_start[seg], e = seg_start[seg + 1];

    // q0 at this lane's 8 cols, from biases (step-0 LSTM with h=c=0)
    vf4 qa, qb;
    {
        int c = l16 * 8;
        vf4 bi0 = *(const vf4*)(b_ih + c) + *(const vf4*)(b_hh + c);
        vf4 bi1 = *(const vf4*)(b_ih + c + 4) + *(const vf4*)(b_hh + c + 4);
        vf4 bg0 = *(const vf4*)(b_ih + 2 * HDIM + c) + *(const vf4*)(b_hh + 2 * HDIM + c);
        vf4 bg1 = *(const vf4*)(b_ih + 2 * HDIM + c + 4) + *(const vf4*)(b_hh + 2 * HDIM + c + 4);
        vf4 bo0 = *(const vf4*)(b_ih + 3 * HDIM + c) + *(const vf4*)(b_hh + 3 * HDIM + c);
        vf4 bo1 = *(const vf4*)(b_ih + 3 * HDIM + c + 4) + *(const vf4*)(b_hh + 3 * HDIM + c + 4);
#pragma unroll
        for (int j = 0; j < 4; ++j) {
            float c0 = sigm(bi0[j]) * ftanh(bg0[j]);
            qa[j] = sigm(bo0[j]) * ftanh(c0);
            float c1 = sigm(bi1[j]) * ftanh(bg1[j]);
            qb[j] = sigm(bo1[j]) * ftanh(c1);
        }
    }

    float m0 = 0.0f, d0 = 0.0f, m1 = 0.0f, d1 = 0.0f;
    vf4 ra0 = {0.f, 0.f, 0.f, 0.f}, rb0 = {0.f, 0.f, 0.f, 0.f};
    vf4 ra1 = {0.f, 0.f, 0.f, 0.f}, rb1 = {0.f, 0.f, 0.f, 0.f};

    int base = s;
#pragma unroll 1
    for (; base + 16 <= e; base += 16) {
        vf4 xa[4], xb[4];
        float p[4];
#pragma unroll
        for (int t = 0; t < 4; ++t) {
            const float* xr = x + (size_t)(base + quarter + 4 * t) * HDIM + l16 * 8;
            xa[t] = ldnt4(xr);
            xb[t] = ldnt4(xr + 4);
        }
#pragma unroll
        for (int t = 0; t < 4; ++t) {
            u16x8 cv;
            cv[0] = f2bf(xa[t].x); cv[1] = f2bf(xa[t].y); cv[2] = f2bf(xa[t].z); cv[3] = f2bf(xa[t].w);
            cv[4] = f2bf(xb[t].x); cv[5] = f2bf(xb[t].y); cv[6] = f2bf(xb[t].z); cv[7] = f2bf(xb[t].w);
            *(u16x8*)(x16 + (size_t)(base + quarter + 4 * t) * HDIM + l16 * 8) = cv;
            p[t] = dot4(xa[t], qa) + dot4(xb[t], qb);
        }
        SHFL16(p[0]) SHFL16(p[1]) SHFL16(p[2]) SHFL16(p[3])
        UPD(m0, d0, ra0, rb0, p[0], xa[0], xb[0])
        UPD(m1, d1, ra1, rb1, p[1], xa[1], xb[1])
        UPD(m0, d0, ra0, rb0, p[2], xa[2], xb[2])
        UPD(m1, d1, ra1, rb1, p[3], xa[3], xb[3])
    }
#pragma unroll 1
    for (; base < e; base += 4) {  // masked 4-row tail
        int row = base + quarter;
        int rl = min(row, e - 1);
        const float* xr = x + (size_t)rl * HDIM + l16 * 8;
        vf4 xa = ldnt4(xr), xb = ldnt4(xr + 4);
        u16x8 cv;
        cv[0] = f2bf(xa.x); cv[1] = f2bf(xa.y); cv[2] = f2bf(xa.z); cv[3] = f2bf(xa.w);
        cv[4] = f2bf(xb.x); cv[5] = f2bf(xb.y); cv[6] = f2bf(xb.z); cv[7] = f2bf(xb.w);
        *(u16x8*)(x16 + (size_t)rl * HDIM + l16 * 8) = cv;
        float p = dot4(xa, qa) + dot4(xb, qb);
        SHFL16(p)
        if (row >= e) p = -1e30f;
        UPD(m0, d0, ra0, rb0, p, xa, xb)
    }
    MERGE_AND_WRITE()
}

// ---- passes 2,3: bf16 x attention, 16-row main loop. rev=1 -> serpentine.
__global__ __launch_bounds__(256) void k_attn_b16(const unsigned short* __restrict__ x16,
                                                  const float* __restrict__ q,
                                                  const int* __restrict__ seg_start,
                                                  float* __restrict__ r_out, int ldr, int col_off,
                                                  int B, int rev) {
    int wave = threadIdx.x >> 6;
    int lane = threadIdx.x & 63;
    int l16 = lane & 15;
    int quarter = lane >> 4;
    int gid = (blockIdx.x << 2) + wave;
    if (gid >= B) return;
    int seg = rev ? (B - 1 - gid) : gid;
    int s = seg_start[seg], e = seg_start[seg + 1];

    const float* qrow = q + (size_t)seg * HDIM + l16 * 8;
    vf4 qa = *(const vf4*)qrow;
    vf4 qb = *(const vf4*)(qrow + 4);

    float m0 = 0.0f, d0 = 0.0f, m1 = 0.0f, d1 = 0.0f;
    vf4 ra0 = {0.f, 0.f, 0.f, 0.f}, rb0 = {0.f, 0.f, 0.f, 0.f};
    vf4 ra1 = {0.f, 0.f, 0.f, 0.f}, rb1 = {0.f, 0.f, 0.f, 0.f};

    int base = s;
#pragma unroll 1
    for (; base + 16 <= e; base += 16) {
        vf4 xa[4], xb[4];
        float p[4];
#pragma unroll
        for (int t = 0; t < 4; ++t) {
            const unsigned short* xr = x16 + (size_t)(base + quarter + 4 * t) * HDIM + l16 * 8;
            u16x8 u = *(const u16x8*)xr;
            xa[t] = vf4{bf2f(u[0]), bf2f(u[1]), bf2f(u[2]), bf2f(u[3])};
            xb[t] = vf4{bf2f(u[4]), bf2f(u[5]), bf2f(u[6]), bf2f(u[7])};
        }
#pragma unroll
        for (int t = 0; t < 4; ++t) p[t] = dot4(xa[t], qa) + dot4(xb[t], qb);
        SHFL16(p[0]) SHFL16(p[1]) SHFL16(p[2]) SHFL16(p[3])
        UPD(m0, d0, ra0, rb0, p[0], xa[0], xb[0])
        UPD(m1, d1, ra1, rb1, p[1], xa[1], xb[1])
        UPD(m0, d0, ra0, rb0, p[2], xa[2], xb[2])
        UPD(m1, d1, ra1, rb1, p[3], xa[3], xb[3])
    }
#pragma unroll 1
    for (; base < e; base += 4) {
        int row = base + quarter;
        const unsigned short* xr = x16 + (size_t)min(row, e - 1) * HDIM + l16 * 8;
        u16x8 u = *(const u16x8*)xr;
        vf4 xa = {bf2f(u[0]), bf2f(u[1]), bf2f(u[2]), bf2f(u[3])};
        vf4 xb = {bf2f(u[4]), bf2f(u[5]), bf2f(u[6]), bf2f(u[7])};
        float p = dot4(xa, qa) + dot4(xb, qb);
        SHFL16(p)
        if (row >= e) p = -1e30f;
        UPD(m0, d0, ra0, rb0, p, xa, xb)
    }
    MERGE_AND_WRITE()
}

// ---- step-1 GEMM + LSTM: K=128 (r only). gates = r*Wc_r^T + gh0 + bias;
// c_prev = c0[hidx] recomputed from biases. 128x64 tile, 8x4 acc (proven shape).
__global__ __launch_bounds__(256) void k_gemm_lstm1(const float* __restrict__ r_prev,
                                                    const float* __restrict__ Wc,
                                                    const float* __restrict__ gh0,
                                                    const float* __restrict__ b_ih,
                                                    const float* __restrict__ b_hh,
                                                    float* __restrict__ h_new,
                                                    float* __restrict__ c_new) {
    __shared__ float As[128 * TS];
    __shared__ float Ws[64 * TS];
    int ct = blockIdx.y;
    int rb = blockIdx.x * 128;
    int tid = threadIdx.x;
    int tx = tid & 15, ty = tid >> 4;
    float acc[8][4];
#pragma unroll
    for (int i = 0; i < 8; ++i)
#pragma unroll
        for (int j = 0; j < 4; ++j) acc[i][j] = 0.0f;

    for (int kc = 0; kc < 4; ++kc) {  // K chunks of 32 over r (Wc cols 128..255)
        int kbase = kc * 32;
#pragma unroll
        for (int i = 0; i < 4; ++i) {
            int li = tid + i * 256;
            int row = li >> 3;
            int c4 = (li & 7) * 4;
            *(vf4*)&As[row * TS + c4] = *(const vf4*)(r_prev + (size_t)(rb + row) * HDIM + kbase + c4);
        }
#pragma unroll
        for (int i = 0; i < 2; ++i) {
            int li = tid + i * 256;
            int col = li >> 3;
            int c4 = (li & 7) * 4;
            int g = ct * 16 + (col & 15) + 128 * (col >> 4);
            *(vf4*)&Ws[col * TS + c4] = *(const vf4*)(Wc + (size_t)g * 256 + 128 + kbase + c4);
        }
        __syncthreads();
#pragma unroll
        for (int k = 0; k < 32; k += 4) {
            vf4 a[8], b[4];
#pragma unroll
            for (int i = 0; i < 8; ++i) a[i] = *(vf4*)&As[(ty + 16 * i) * TS + k];
#pragma unroll
            for (int j = 0; j < 4; ++j) b[j] = *(vf4*)&Ws[(tx + 16 * j) * TS + k];
#pragma unroll
            for (int i = 0; i < 8; ++i)
#pragma unroll
                for (int j = 0; j < 4; ++j) {
                    acc[i][j] += a[i].x * b[j].x + a[i].y * b[j].y +
                                 a[i].z * b[j].z + a[i].w * b[j].w;
                }
        }
        __syncthreads();
    }
    int hidx = ct * 16 + tx;
    float bi = b_ih[hidx] + b_hh[hidx] + gh0[hidx];
    float bf = b_ih[HDIM + hidx] + b_hh[HDIM + hidx] + gh0[HDIM + hidx];
    float bg = b_ih[2 * HDIM + hidx] + b_hh[2 * HDIM + hidx] + gh0[2 * HDIM + hidx];
    float bo = b_ih[3 * HDIM + hidx] + b_hh[3 * HDIM + hidx] + gh0[3 * HDIM + hidx];
    // c0 from step-0 (bias-only gates)
    float bi0 = b_ih[hidx] + b_hh[hidx];
    float bg0 = b_ih[2 * HDIM + hidx] + b_hh[2 * HDIM + hidx];
    float c0 = sigm(bi0) * ftanh(bg0);
#pragma unroll
    for (int i = 0; i < 8; ++i) {
        int row = rb + ty + 16 * i;
        float gi = acc[i][0] + bi;
        float gf = acc[i][1] + bf;
        float gg = acc[i][2] + bg;
        float go = acc[i][3] + bo;
        float cn = sigm(gf) * c0 + sigm(gi) * ftanh(gg);
        float hn = sigm(go) * ftanh(cn);
        c_new[(size_t)row * HDIM + hidx] = cn;
        h_new[(size_t)row * HDIM + hidx] = hn;
    }
}

// ---- step-2 GEMM + LSTM: K=256 (h | r), unchanged proven kernel.
__global__ __launch_bounds__(256) void k_gemm_lstm(const float* __restrict__ h_prev,
                                                   const float* __restrict__ r_prev,
                                                   const float* __restrict__ c_prev,
                                                   const float* __restrict__ Wc,
                                                   const float* __restrict__ b_ih,
                                                   const float* __restrict__ b_hh,
                                                   float* __restrict__ h_new,
                                                   float* __restrict__ c_new,
                                                   float* __restrict__ h_mirror) {
    __shared__ float As[128 * TS];
    __shared__ float Ws[64 * TS];
    int ct = blockIdx.y;
    int rb = blockIdx.x * 128;
    int tid = threadIdx.x;
    int tx = tid & 15, ty = tid >> 4;
    float acc[8][4];
#pragma unroll
    for (int i = 0; i < 8; ++i)
#pragma unroll
        for (int j = 0; j < 4; ++j) acc[i][j] = 0.0f;

    for (int kc = 0; kc < 8; ++kc) {
        const float* src = (kc < 4) ? h_prev : r_prev;
        int kbase = (kc & 3) * 32;
#pragma unroll
        for (int i = 0; i < 4; ++i) {
            int li = tid + i * 256;
            int row = li >> 3;
            int c4 = (li & 7) * 4;
            *(vf4*)&As[row * TS + c4] = *(const vf4*)(src + (size_t)(rb + row) * HDIM + kbase + c4);
        }
#pragma unroll
        for (int i = 0; i < 2; ++i) {
            int li = tid + i * 256;
            int col = li >> 3;
            int c4 = (li & 7) * 4;
            int g = ct * 16 + (col & 15) + 128 * (col >> 4);
            *(vf4*)&Ws[col * TS + c4] = *(const vf4*)(Wc + (size_t)g * 256 + kc * 32 + c4);
        }
        __syncthreads();
#pragma unroll
        for (int k = 0; k < 32; k += 4) {
            vf4 a[8], b[4];
#pragma unroll
            for (int i = 0; i < 8; ++i) a[i] = *(vf4*)&As[(ty + 16 * i) * TS + k];
#pragma unroll
            for (int j = 0; j < 4; ++j) b[j] = *(vf4*)&Ws[(tx + 16 * j) * TS + k];
#pragma unroll
            for (int i = 0; i < 8; ++i)
#pragma unroll
                for (int j = 0; j < 4; ++j) {
                    acc[i][j] += a[i].x * b[j].x + a[i].y * b[j].y +
                                 a[i].z * b[j].z + a[i].w * b[j].w;
                }
        }
        __syncthreads();
    }
    int hidx = ct * 16 + tx;
    float bi = b_ih[hidx] + b_hh[hidx];
    float bf = b_ih[HDIM + hidx] + b_hh[HDIM + hidx];
    float bg = b_ih[2 * HDIM + hidx] + b_hh[2 * HDIM + hidx];
    float bo = b_ih[3 * HDIM + hidx] + b_hh[3 * HDIM + hidx];
#pragma unroll
    for (int i = 0; i < 8; ++i) {
        int row = rb + ty + 16 * i;
        float gi = acc[i][0] + bi;
        float gf = acc[i][1] + bf;
        float gg = acc[i][2] + bg;
        float go = acc[i][3] + bo;
        float cp = c_prev[(size_t)row * HDIM + hidx];
        float cn = sigm(gf) * cp + sigm(gi) * ftanh(gg);
        float hn = sigm(go) * ftanh(cn);
        c_new[(size_t)row * HDIM + hidx] = cn;
        h_new[(size_t)row * HDIM + hidx] = hn;
        if (h_mirror) h_mirror[(size_t)row * 2 * HDIM + hidx] = hn;
    }
}

extern "C" void kernel_launch(void* const* d_in, const int* in_sizes, int n_in,
                              void* d_out, int out_size, void* d_ws, size_t ws_size,
                              hipStream_t stream) {
    const float* x = (const float*)d_in[0];
    const int* batch_vec = (const int*)d_in[1];
    const float* W_ih = (const float*)d_in[2];
    const float* W_hh = (const float*)d_in[3];
    const float* b_ih = (const float*)d_in[4];
    const float* b_hh = (const float*)d_in[5];
    float* out = (float*)d_out;

    int N = in_sizes[1];
    int B = out_size / (2 * HDIM);

    char* ws = (char*)d_ws;
    float* Wc = (float*)ws;            ws += (size_t)G4 * 2 * HDIM * 4;
    float* gh0 = (float*)ws;           ws += (size_t)G4 * 4;
    float* h_a = (float*)ws;           ws += (size_t)B * HDIM * 4;
    float* h_b = (float*)ws;           ws += (size_t)B * HDIM * 4;
    float* cbuf = (float*)ws;          ws += (size_t)B * HDIM * 4;
    float* rbuf = (float*)ws;          ws += (size_t)B * HDIM * 4;
    int* seg = (int*)ws;               ws += (size_t)(B + 1) * 4;
    ws = (char*)(((size_t)ws + 255) & ~(size_t)255);
    unsigned short* x16 = (unsigned short*)ws;  // N*128*2 = 256 MB

    k_setup<<<512, 256, 0, stream>>>(W_ih, W_hh, batch_vec, N, B, Wc, seg);
    k_head<<<2, 256, 0, stream>>>(Wc, b_ih, b_hh, gh0);

    dim3 ggrid(B / 128, 8);
    // pass 1 (fwd, fp32 + cvt) -> GEMM1 (K=128) -> pass 2 (rev, bf16) -> GEMM2 -> pass 3 (fwd, bf16)
    k_attn_cvt<<<(B + 3) / 4, 256, 0, stream>>>(x, x16, b_ih, b_hh, seg, rbuf, B);
    k_gemm_lstm1<<<ggrid, 256, 0, stream>>>(rbuf, Wc, gh0, b_ih, b_hh, h_b, cbuf);
    k_attn_b16<<<(B + 3) / 4, 256, 0, stream>>>(x16, h_b, seg, rbuf, HDIM, 0, B, 1);
    k_gemm_lstm<<<ggrid, 256, 0, stream>>>(h_b, rbuf, cbuf, Wc, b_ih, b_hh, h_a, cbuf, out);
    k_attn_b16<<<(B + 3) / 4, 256, 0, stream>>>(x16, h_a, seg, out, 2 * HDIM, HDIM, B, 0);
}

// Round 8
// 476.658 us; speedup vs baseline: 6.9155x; 1.0046x over previous
//
#include <hip/hip_runtime.h>
#include <math.h>

#define HDIM 128
#define G4 512  // 4*H
#define TS 36   // GEMM LDS row stride (floats)

typedef float vf4 __attribute__((ext_vector_type(4)));
typedef unsigned short u16x8 __attribute__((ext_vector_type(8)));

__device__ __forceinline__ float sigm(float v) { return 1.0f / (1.0f + __expf(-v)); }
__device__ __forceinline__ float ftanh(float v) {
    return 1.0f - 2.0f / (__expf(2.0f * v) + 1.0f);
}
__device__ __forceinline__ float dot4(vf4 a, vf4 b) {
    return a.x * b.x + a.y * b.y + a.z * b.z + a.w * b.w;
}
__device__ __forceinline__ vf4 ldnt4(const float* p) {
    return __builtin_nontemporal_load((const vf4*)p);
}
__device__ __forceinline__ unsigned short f2bf(float f) {  // RTNE
    unsigned u = __float_as_uint(f);
    u += 0x7fff + ((u >> 16) & 1);
    return (unsigned short)(u >> 16);
}
__device__ __forceinline__ float bf2f(unsigned short h) {
    return __uint_as_float(((unsigned)h) << 16);
}

// ---- setup: Wc prep + segment starts + gh0 (= Wc_h . h0, h0 from biases)
__global__ __launch_bounds__(256) void k_setup(const float* __restrict__ W_ih,
                                               const float* __restrict__ W_hh,
                                               const float* __restrict__ b_ih,
                                               const float* __restrict__ b_hh,
                                               const int* __restrict__ batch_vec, int N, int B,
                                               float* __restrict__ Wc, int* __restrict__ seg_start,
                                               float* __restrict__ gh0) {
    __shared__ float h0s[HDIM];
    int t = blockIdx.x * 256 + threadIdx.x;
    if (blockIdx.x < 2) {  // blocks 0,1 also compute gh0 (g = t in [0,512))
        if (threadIdx.x < HDIM) {
            int hid = threadIdx.x;
            float bi = b_ih[hid] + b_hh[hid];
            float bg = b_ih[2 * HDIM + hid] + b_hh[2 * HDIM + hid];
            float bo = b_ih[3 * HDIM + hid] + b_hh[3 * HDIM + hid];
            float c0 = sigm(bi) * ftanh(bg);
            h0s[hid] = sigm(bo) * ftanh(c0);
        }
        __syncthreads();
        if (t < G4) {
            float s = 0.0f;
#pragma unroll
            for (int k = 0; k < HDIM; k += 4) {
                vf4 wi = *(const vf4*)(W_ih + (size_t)t * 256 + k);
                vf4 wh = *(const vf4*)(W_hh + (size_t)t * HDIM + k);
                s += (wi.x + wh.x) * h0s[k] + (wi.y + wh.y) * h0s[k + 1] +
                     (wi.z + wh.z) * h0s[k + 2] + (wi.w + wh.w) * h0s[k + 3];
            }
            gh0[t] = s;
        }
    }
    if (t < G4 * 2 * HDIM) {  // Wc[512][256] = [W_ih[:,:128]+W_hh | W_ih[:,128:]]
        int g = t >> 8;
        int k = t & 255;
        float w = W_ih[g * 256 + k];
        if (k < HDIM) w += W_hh[g * HDIM + k];
        Wc[t] = w;
    }
    if (t <= B) {  // lower_bound over sorted batch_vec
        int lo = 0, hi = N;
        while (lo < hi) {
            int mid = (lo + hi) >> 1;
            if (batch_vec[mid] < t) lo = mid + 1; else hi = mid;
        }
        seg_start[t] = lo;
    }
}

// ---- linear fp32 -> bf16 conversion. Nontemporal reads (don't pollute L3);
// normal writes (x16 = 256 MB lands in L3 and stays for all 3 attn passes).
__global__ __launch_bounds__(256) void k_cvt(const float* __restrict__ x,
                                             unsigned short* __restrict__ x16,
                                             long total8) {
    long i = (long)blockIdx.x * 256 + threadIdx.x;
    long stride = (long)gridDim.x * 256;
    for (; i < total8; i += stride) {
        vf4 a = ldnt4(x + i * 8);
        vf4 b = ldnt4(x + i * 8 + 4);
        u16x8 c;
        c[0] = f2bf(a.x); c[1] = f2bf(a.y); c[2] = f2bf(a.z); c[3] = f2bf(a.w);
        c[4] = f2bf(b.x); c[5] = f2bf(b.y); c[6] = f2bf(b.z); c[7] = f2bf(b.w);
        *(u16x8*)(x16 + i * 8) = c;
    }
}

#define UPD(m_, d_, ra_, rb_, p_, xa_, xb_)  \
    {                                        \
        float mn_ = fmaxf(m_, p_);           \
        float sc_ = __expf(m_ - mn_);        \
        float pe_ = __expf(p_ - mn_);        \
        d_ = d_ * sc_ + pe_;                 \
        ra_ = ra_ * sc_ + pe_ * xa_;         \
        rb_ = rb_ * sc_ + pe_ * xb_;         \
        m_ = mn_;                            \
    }

#define SHFL16(p_)                  \
    p_ += __shfl_xor(p_, 1, 64);    \
    p_ += __shfl_xor(p_, 2, 64);    \
    p_ += __shfl_xor(p_, 4, 64);    \
    p_ += __shfl_xor(p_, 8, 64);

// ---- attention over bf16 x. q from buffer (stride ldq) or, if q==nullptr,
// q0 recomputed from biases. XCD-bijective block swizzle for read locality.
__global__ __launch_bounds__(256) void k_attn(const unsigned short* __restrict__ x16,
                                              const float* __restrict__ q, int ldq,
                                              const float* __restrict__ b_ih,
                                              const float* __restrict__ b_hh,
                                              const int* __restrict__ seg_start,
                                              float* __restrict__ r_out, int ldr, int col_off,
                                              int B) {
    int wave = threadIdx.x >> 6;
    int lane = threadIdx.x & 63;
    int l16 = lane & 15;
    int quarter = lane >> 4;
    // bijective XCD swizzle (m204): contiguous segment range per XCD
    int nblk = gridDim.x;
    int bid = blockIdx.x;
    int q8 = nblk >> 3, r8 = nblk & 7;
    int xcd = bid & 7, pos = bid >> 3;
    int nb = (xcd < r8 ? xcd * (q8 + 1) : r8 * (q8 + 1) + (xcd - r8) * q8) + pos;
    int seg = (nb << 2) + wave;
    if (seg >= B) return;
    int s = seg_start[seg], e = seg_start[seg + 1];

    vf4 qa, qb;
    if (q) {
        const float* qrow = q + (size_t)seg * ldq + l16 * 8;
        qa = *(const vf4*)qrow;
        qb = *(const vf4*)(qrow + 4);
    } else {  // q0 from biases (step-0 LSTM with h=c=0)
        int c = l16 * 8;
        vf4 bi0 = *(const vf4*)(b_ih + c) + *(const vf4*)(b_hh + c);
        vf4 bi1 = *(const vf4*)(b_ih + c + 4) + *(const vf4*)(b_hh + c + 4);
        vf4 bg0 = *(const vf4*)(b_ih + 2 * HDIM + c) + *(const vf4*)(b_hh + 2 * HDIM + c);
        vf4 bg1 = *(const vf4*)(b_ih + 2 * HDIM + c + 4) + *(const vf4*)(b_hh + 2 * HDIM + c + 4);
        vf4 bo0 = *(const vf4*)(b_ih + 3 * HDIM + c) + *(const vf4*)(b_hh + 3 * HDIM + c);
        vf4 bo1 = *(const vf4*)(b_ih + 3 * HDIM + c + 4) + *(const vf4*)(b_hh + 3 * HDIM + c + 4);
#pragma unroll
        for (int j = 0; j < 4; ++j) {
            float c0 = sigm(bi0[j]) * ftanh(bg0[j]);
            qa[j] = sigm(bo0[j]) * ftanh(c0);
            float c1 = sigm(bi1[j]) * ftanh(bg1[j]);
            qb[j] = sigm(bo1[j]) * ftanh(c1);
        }
    }

    float m0 = 0.0f, d0 = 0.0f, m1 = 0.0f, d1 = 0.0f;
    vf4 ra0 = {0.f, 0.f, 0.f, 0.f}, rb0 = {0.f, 0.f, 0.f, 0.f};
    vf4 ra1 = {0.f, 0.f, 0.f, 0.f}, rb1 = {0.f, 0.f, 0.f, 0.f};

    int base = s;
#pragma unroll 1
    for (; base + 16 <= e; base += 16) {
        vf4 xa[4], xb[4];
        float p[4];
#pragma unroll
        for (int t = 0; t < 4; ++t) {
            const unsigned short* xr = x16 + (size_t)(base + quarter + 4 * t) * HDIM + l16 * 8;
            u16x8 u = *(const u16x8*)xr;
            xa[t] = vf4{bf2f(u[0]), bf2f(u[1]), bf2f(u[2]), bf2f(u[3])};
            xb[t] = vf4{bf2f(u[4]), bf2f(u[5]), bf2f(u[6]), bf2f(u[7])};
        }
#pragma unroll
        for (int t = 0; t < 4; ++t) p[t] = dot4(xa[t], qa) + dot4(xb[t], qb);
        SHFL16(p[0]) SHFL16(p[1]) SHFL16(p[2]) SHFL16(p[3])
        UPD(m0, d0, ra0, rb0, p[0], xa[0], xb[0])
        UPD(m1, d1, ra1, rb1, p[1], xa[1], xb[1])
        UPD(m0, d0, ra0, rb0, p[2], xa[2], xb[2])
        UPD(m1, d1, ra1, rb1, p[3], xa[3], xb[3])
    }
#pragma unroll 1
    for (; base < e; base += 4) {  // masked 4-row tail
        int row = base + quarter;
        const unsigned short* xr = x16 + (size_t)min(row, e - 1) * HDIM + l16 * 8;
        u16x8 u = *(const u16x8*)xr;
        vf4 xa = {bf2f(u[0]), bf2f(u[1]), bf2f(u[2]), bf2f(u[3])};
        vf4 xb = {bf2f(u[4]), bf2f(u[5]), bf2f(u[6]), bf2f(u[7])};
        float p = dot4(xa, qa) + dot4(xb, qb);
        SHFL16(p)
        if (row >= e) p = -1e30f;
        UPD(m0, d0, ra0, rb0, p, xa, xb)
    }
    {  // merge state1 -> state0
        float M = fmaxf(m0, m1);
        float w0 = __expf(m0 - M), w1 = __expf(m1 - M);
        d0 = d0 * w0 + d1 * w1;
        ra0 = ra0 * w0 + ra1 * w1;
        rb0 = rb0 * w0 + rb1 * w1;
        m0 = M;
    }
#pragma unroll
    for (int off = 16; off <= 32; off <<= 1) {  // merge the 4 quarter-states
        float om = __shfl_xor(m0, off, 64);
        float M = fmaxf(m0, om);
        float w = __expf(m0 - M);
        d0 *= w; ra0 *= w; rb0 *= w;
        d0 += __shfl_xor(d0, off, 64);
        ra0.x += __shfl_xor(ra0.x, off, 64);
        ra0.y += __shfl_xor(ra0.y, off, 64);
        ra0.z += __shfl_xor(ra0.z, off, 64);
        ra0.w += __shfl_xor(ra0.w, off, 64);
        rb0.x += __shfl_xor(rb0.x, off, 64);
        rb0.y += __shfl_xor(rb0.y, off, 64);
        rb0.z += __shfl_xor(rb0.z, off, 64);
        rb0.w += __shfl_xor(rb0.w, off, 64);
        m0 = M;
    }
    float inv = (d0 > 0.0f) ? 1.0f / d0 : 0.0f;
    if (quarter == 0) {
        float* dst = r_out + (size_t)seg * ldr + col_off + l16 * 8;
        *(vf4*)dst = ra0 * inv;
        *(vf4*)(dst + 4) = rb0 * inv;
    }
}

// ---- step-1 GEMM + LSTM: K=128 (r only); gh0 folded into bias; c0 recomputed.
__global__ __launch_bounds__(256) void k_gemm_lstm1(const float* __restrict__ r_prev,
                                                    const float* __restrict__ Wc,
                                                    const float* __restrict__ gh0,
                                                    const float* __restrict__ b_ih,
                                                    const float* __restrict__ b_hh,
                                                    float* __restrict__ h_new,
                                                    float* __restrict__ c_new) {
    __shared__ float As[128 * TS];
    __shared__ float Ws[64 * TS];
    int ct = blockIdx.y;
    int rb = blockIdx.x * 128;
    int tid = threadIdx.x;
    int tx = tid & 15, ty = tid >> 4;
    float acc[8][4];
#pragma unroll
    for (int i = 0; i < 8; ++i)
#pragma unroll
        for (int j = 0; j < 4; ++j) acc[i][j] = 0.0f;

    for (int kc = 0; kc < 4; ++kc) {
        int kbase = kc * 32;
#pragma unroll
        for (int i = 0; i < 4; ++i) {
            int li = tid + i * 256;
            int row = li >> 3;
            int c4 = (li & 7) * 4;
            *(vf4*)&As[row * TS + c4] = *(const vf4*)(r_prev + (size_t)(rb + row) * HDIM + kbase + c4);
        }
#pragma unroll
        for (int i = 0; i < 2; ++i) {
            int li = tid + i * 256;
            int col = li >> 3;
            int c4 = (li & 7) * 4;
            int g = ct * 16 + (col & 15) + 128 * (col >> 4);
            *(vf4*)&Ws[col * TS + c4] = *(const vf4*)(Wc + (size_t)g * 256 + 128 + kbase + c4);
        }
        __syncthreads();
#pragma unroll
        for (int k = 0; k < 32; k += 4) {
            vf4 a[8], b[4];
#pragma unroll
            for (int i = 0; i < 8; ++i) a[i] = *(vf4*)&As[(ty + 16 * i) * TS + k];
#pragma unroll
            for (int j = 0; j < 4; ++j) b[j] = *(vf4*)&Ws[(tx + 16 * j) * TS + k];
#pragma unroll
            for (int i = 0; i < 8; ++i)
#pragma unroll
                for (int j = 0; j < 4; ++j) {
                    acc[i][j] += a[i].x * b[j].x + a[i].y * b[j].y +
                                 a[i].z * b[j].z + a[i].w * b[j].w;
                }
        }
        __syncthreads();
    }
    int hidx = ct * 16 + tx;
    float bi = b_ih[hidx] + b_hh[hidx] + gh0[hidx];
    float bf = b_ih[HDIM + hidx] + b_hh[HDIM + hidx] + gh0[HDIM + hidx];
    float bg = b_ih[2 * HDIM + hidx] + b_hh[2 * HDIM + hidx] + gh0[2 * HDIM + hidx];
    float bo = b_ih[3 * HDIM + hidx] + b_hh[3 * HDIM + hidx] + gh0[3 * HDIM + hidx];
    float bi0 = b_ih[hidx] + b_hh[hidx];
    float bg0 = b_ih[2 * HDIM + hidx] + b_hh[2 * HDIM + hidx];
    float c0 = sigm(bi0) * ftanh(bg0);
#pragma unroll
    for (int i = 0; i < 8; ++i) {
        int row = rb + ty + 16 * i;
        float gi = acc[i][0] + bi;
        float gf = acc[i][1] + bf;
        float gg = acc[i][2] + bg;
        float go = acc[i][3] + bo;
        float cn = sigm(gf) * c0 + sigm(gi) * ftanh(gg);
        float hn = sigm(go) * ftanh(cn);
        c_new[(size_t)row * HDIM + hidx] = cn;
        h_new[(size_t)row * HDIM + hidx] = hn;
    }
}

// ---- step-2 GEMM + LSTM: K=256 (h | r); h written only into out[:, :128].
__global__ __launch_bounds__(256) void k_gemm_lstm(const float* __restrict__ h_prev,
                                                   const float* __restrict__ r_prev,
                                                   const float* __restrict__ c_prev,
                                                   const float* __restrict__ Wc,
                                                   const float* __restrict__ b_ih,
                                                   const float* __restrict__ b_hh,
                                                   float* __restrict__ h_mirror) {
    __shared__ float As[128 * TS];
    __shared__ float Ws[64 * TS];
    int ct = blockIdx.y;
    int rb = blockIdx.x * 128;
    int tid = threadIdx.x;
    int tx = tid & 15, ty = tid >> 4;
    float acc[8][4];
#pragma unroll
    for (int i = 0; i < 8; ++i)
#pragma unroll
        for (int j = 0; j < 4; ++j) acc[i][j] = 0.0f;

    for (int kc = 0; kc < 8; ++kc) {
        const float* src = (kc < 4) ? h_prev : r_prev;
        int kbase = (kc & 3) * 32;
#pragma unroll
        for (int i = 0; i < 4; ++i) {
            int li = tid + i * 256;
            int row = li >> 3;
            int c4 = (li & 7) * 4;
            *(vf4*)&As[row * TS + c4] = *(const vf4*)(src + (size_t)(rb + row) * HDIM + kbase + c4);
        }
#pragma unroll
        for (int i = 0; i < 2; ++i) {
            int li = tid + i * 256;
            int col = li >> 3;
            int c4 = (li & 7) * 4;
            int g = ct * 16 + (col & 15) + 128 * (col >> 4);
            *(vf4*)&Ws[col * TS + c4] = *(const vf4*)(Wc + (size_t)g * 256 + kc * 32 + c4);
        }
        __syncthreads();
#pragma unroll
        for (int k = 0; k < 32; k += 4) {
            vf4 a[8], b[4];
#pragma unroll
            for (int i = 0; i < 8; ++i) a[i] = *(vf4*)&As[(ty + 16 * i) * TS + k];
#pragma unroll
            for (int j = 0; j < 4; ++j) b[j] = *(vf4*)&Ws[(tx + 16 * j) * TS + k];
#pragma unroll
            for (int i = 0; i < 8; ++i)
#pragma unroll
                for (int j = 0; j < 4; ++j) {
                    acc[i][j] += a[i].x * b[j].x + a[i].y * b[j].y +
                                 a[i].z * b[j].z + a[i].w * b[j].w;
                }
        }
        __syncthreads();
    }
    int hidx = ct * 16 + tx;
    float bi = b_ih[hidx] + b_hh[hidx];
    float bf = b_ih[HDIM + hidx] + b_hh[HDIM + hidx];
    float bg = b_ih[2 * HDIM + hidx] + b_hh[2 * HDIM + hidx];
    float bo = b_ih[3 * HDIM + hidx] + b_hh[3 * HDIM + hidx];
#pragma unroll
    for (int i = 0; i < 8; ++i) {
        int row = rb + ty + 16 * i;
        float gi = acc[i][0] + bi;
        float gf = acc[i][1] + bf;
        float gg = acc[i][2] + bg;
        float go = acc[i][3] + bo;
        float cp = c_prev[(size_t)row * HDIM + hidx];
        float cn = sigm(gf) * cp + sigm(gi) * ftanh(gg);
        float hn = sigm(go) * ftanh(cn);
        h_mirror[(size_t)row * 2 * HDIM + hidx] = hn;
    }
}

extern "C" void kernel_launch(void* const* d_in, const int* in_sizes, int n_in,
                              void* d_out, int out_size, void* d_ws, size_t ws_size,
                              hipStream_t stream) {
    const float* x = (const float*)d_in[0];
    const int* batch_vec = (const int*)d_in[1];
    const float* W_ih = (const float*)d_in[2];
    const float* W_hh = (const float*)d_in[3];
    const float* b_ih = (const float*)d_in[4];
    const float* b_hh = (const float*)d_in[5];
    float* out = (float*)d_out;

    int N = in_sizes[1];
    int B = out_size / (2 * HDIM);

    char* ws = (char*)d_ws;
    float* Wc = (float*)ws;            ws += (size_t)G4 * 2 * HDIM * 4;
    float* gh0 = (float*)ws;           ws += (size_t)G4 * 4;
    float* h_b = (float*)ws;           ws += (size_t)B * HDIM * 4;
    float* cbuf = (float*)ws;          ws += (size_t)B * HDIM * 4;
    float* rbuf = (float*)ws;          ws += (size_t)B * HDIM * 4;
    int* seg = (int*)ws;               ws += (size_t)(B + 1) * 4;
    ws = (char*)(((size_t)ws + 255) & ~(size_t)255);
    unsigned short* x16 = (unsigned short*)ws;  // N*128*2 = 256 MB, ~L3-resident

    k_setup<<<512, 256, 0, stream>>>(W_ih, W_hh, b_ih, b_hh, batch_vec, N, B, Wc, seg, gh0);
    k_cvt<<<2048, 256, 0, stream>>>(x, x16, (long)N * HDIM / 8);

    dim3 ggrid(B / 128, 8);
    int ablk = (B + 3) / 4;
    // pass 1 (q0 from biases) -> GEMM1 (K=128) -> pass 2 -> GEMM2 -> pass 3 (q from out)
    k_attn<<<ablk, 256, 0, stream>>>(x16, nullptr, 0, b_ih, b_hh, seg, rbuf, HDIM, 0, B);
    k_gemm_lstm1<<<ggrid, 256, 0, stream>>>(rbuf, Wc, gh0, b_ih, b_hh, h_b, cbuf);
    k_attn<<<ablk, 256, 0, stream>>>(x16, h_b, HDIM, b_ih, b_hh, seg, rbuf, HDIM, 0, B);
    k_gemm_lstm<<<ggrid, 256, 0, stream>>>(h_b, rbuf, cbuf, Wc, b_ih, b_hh, out);
    k_attn<<<ablk, 256, 0, stream>>>(x16, out, 2 * HDIM, b_ih, b_hh, seg, out, 2 * HDIM, HDIM, B);
}

// Round 9
// 456.417 us; speedup vs baseline: 7.2222x; 1.0443x over previous
//
#include <hip/hip_runtime.h>
#include <math.h>

#define HDIM 128
#define G4 512  // 4*H
#define TS 36   // GEMM LDS row stride (floats)

typedef float vf4 __attribute__((ext_vector_type(4)));
typedef unsigned short u16x8 __attribute__((ext_vector_type(8)));

__device__ __forceinline__ float sigm(float v) { return 1.0f / (1.0f + __expf(-v)); }
__device__ __forceinline__ float ftanh(float v) {
    return 1.0f - 2.0f / (__expf(2.0f * v) + 1.0f);
}
__device__ __forceinline__ float dot4(vf4 a, vf4 b) {
    return a.x * b.x + a.y * b.y + a.z * b.z + a.w * b.w;
}
__device__ __forceinline__ vf4 ldnt4(const float* p) {
    return __builtin_nontemporal_load((const vf4*)p);
}
__device__ __forceinline__ unsigned short f2bf(float f) {  // RTNE
    unsigned u = __float_as_uint(f);
    u += 0x7fff + ((u >> 16) & 1);
    return (unsigned short)(u >> 16);
}
__device__ __forceinline__ float bf2f(unsigned short h) {
    return __uint_as_float(((unsigned)h) << 16);
}

// ---- setup: Wc prep + segment starts + gh0 (= Wc_h . h0, h0 from biases)
__global__ __launch_bounds__(256) void k_setup(const float* __restrict__ W_ih,
                                               const float* __restrict__ W_hh,
                                               const float* __restrict__ b_ih,
                                               const float* __restrict__ b_hh,
                                               const int* __restrict__ batch_vec, int N, int B,
                                               float* __restrict__ Wc, int* __restrict__ seg_start,
                                               float* __restrict__ gh0) {
    __shared__ float h0s[HDIM];
    int t = blockIdx.x * 256 + threadIdx.x;
    if (blockIdx.x < 2) {  // blocks 0,1 also compute gh0 (g = t in [0,512))
        if (threadIdx.x < HDIM) {
            int hid = threadIdx.x;
            float bi = b_ih[hid] + b_hh[hid];
            float bg = b_ih[2 * HDIM + hid] + b_hh[2 * HDIM + hid];
            float bo = b_ih[3 * HDIM + hid] + b_hh[3 * HDIM + hid];
            float c0 = sigm(bi) * ftanh(bg);
            h0s[hid] = sigm(bo) * ftanh(c0);
        }
        __syncthreads();
        if (t < G4) {
            float s = 0.0f;
#pragma unroll
            for (int k = 0; k < HDIM; k += 4) {
                vf4 wi = *(const vf4*)(W_ih + (size_t)t * 256 + k);
                vf4 wh = *(const vf4*)(W_hh + (size_t)t * HDIM + k);
                s += (wi.x + wh.x) * h0s[k] + (wi.y + wh.y) * h0s[k + 1] +
                     (wi.z + wh.z) * h0s[k + 2] + (wi.w + wh.w) * h0s[k + 3];
            }
            gh0[t] = s;
        }
    }
    if (t < G4 * 2 * HDIM) {  // Wc[512][256] = [W_ih[:,:128]+W_hh | W_ih[:,128:]]
        int g = t >> 8;
        int k = t & 255;
        float w = W_ih[g * 256 + k];
        if (k < HDIM) w += W_hh[g * HDIM + k];
        Wc[t] = w;
    }
    if (t <= B) {  // lower_bound over sorted batch_vec
        int lo = 0, hi = N;
        while (lo < hi) {
            int mid = (lo + hi) >> 1;
            if (batch_vec[mid] < t) lo = mid + 1; else hi = mid;
        }
        seg_start[t] = lo;
    }
}

#define UPD(m_, d_, ra_, rb_, p_, xa_, xb_)  \
    {                                        \
        float mn_ = fmaxf(m_, p_);           \
        float sc_ = __expf(m_ - mn_);        \
        float pe_ = __expf(p_ - mn_);        \
        d_ = d_ * sc_ + pe_;                 \
        ra_ = ra_ * sc_ + pe_ * xa_;         \
        rb_ = rb_ * sc_ + pe_ * xb_;         \
        m_ = mn_;                            \
    }

#define SHFL16(p_)                  \
    p_ += __shfl_xor(p_, 1, 64);    \
    p_ += __shfl_xor(p_, 2, 64);    \
    p_ += __shfl_xor(p_, 4, 64);    \
    p_ += __shfl_xor(p_, 8, 64);

struct AttState {
    float m0, d0, m1, d1;
    vf4 ra0, rb0, ra1, rb1;
};

__device__ __forceinline__ void init_state(AttState& st) {
    st.m0 = 0.f; st.d0 = 0.f; st.m1 = 0.f; st.d1 = 0.f;
    st.ra0 = vf4{0.f, 0.f, 0.f, 0.f}; st.rb0 = vf4{0.f, 0.f, 0.f, 0.f};
    st.ra1 = vf4{0.f, 0.f, 0.f, 0.f}; st.rb1 = vf4{0.f, 0.f, 0.f, 0.f};
}

__device__ __forceinline__ void compute4(const vf4 xa[4], const vf4 xb[4], int baserow, int e,
                                         vf4 qa, vf4 qb, AttState& st) {
    float p[4];
#pragma unroll
    for (int t = 0; t < 4; ++t) p[t] = dot4(xa[t], qa) + dot4(xb[t], qb);
    SHFL16(p[0]) SHFL16(p[1]) SHFL16(p[2]) SHFL16(p[3])
#pragma unroll
    for (int t = 0; t < 4; ++t)
        if (baserow + t >= e) p[t] = -1e30f;
    UPD(st.m0, st.d0, st.ra0, st.rb0, p[0], xa[0], xb[0])
    UPD(st.m1, st.d1, st.ra1, st.rb1, p[1], xa[1], xb[1])
    UPD(st.m0, st.d0, st.ra0, st.rb0, p[2], xa[2], xb[2])
    UPD(st.m1, st.d1, st.ra1, st.rb1, p[3], xa[3], xb[3])
}

__device__ __forceinline__ void finish_state(AttState& st, float* dst) {
    float M = fmaxf(st.m0, st.m1);
    float w0 = __expf(st.m0 - M), w1 = __expf(st.m1 - M);
    float d = st.d0 * w0 + st.d1 * w1;
    vf4 ra = st.ra0 * w0 + st.ra1 * w1;
    vf4 rb = st.rb0 * w0 + st.rb1 * w1;
    float inv = (d > 0.0f) ? 1.0f / d : 0.0f;
    *(vf4*)dst = ra * inv;
    *(vf4*)(dst + 4) = rb * inv;
}

// segment geometry for quarter-per-segment layout (4 segs/wave, 16/block)
__device__ __forceinline__ int seg_of_block(int bid, int nblk, int rev, int wave, int quarter) {
    int q8 = nblk >> 3, r8 = nblk & 7;
    int xcd = bid & 7, pos = bid >> 3;
    int nb = (xcd < r8 ? xcd * (q8 + 1) : r8 * (q8 + 1) + (xcd - r8) * q8) + pos;
    if (rev) nb = nblk - 1 - nb;
    return nb * 16 + wave * 4 + quarter;
}

// ---- pass 1: fp32 x attention + fused bf16 conversion; q0 from biases.
// Quarter-per-segment, 2-stage software pipeline.
__global__ __launch_bounds__(256) void k_attn_cvt(const float* __restrict__ x,
                                                  unsigned short* __restrict__ x16,
                                                  const float* __restrict__ b_ih,
                                                  const float* __restrict__ b_hh,
                                                  const int* __restrict__ seg_start,
                                                  float* __restrict__ r_out, int B) {
    int wave = threadIdx.x >> 6;
    int lane = threadIdx.x & 63;
    int l16 = lane & 15;
    int quarter = lane >> 4;
    int seg = seg_of_block(blockIdx.x, gridDim.x, 0, wave, quarter);
    int seg_c = min(seg, B - 1);
    int s = seg_start[seg_c], e = seg_start[seg_c + 1];
    if (seg >= B) { s = 0; e = 0; }

    vf4 qa, qb;
    {  // q0 from biases (step-0 LSTM with h=c=0)
        int c = l16 * 8;
        vf4 bi0 = *(const vf4*)(b_ih + c) + *(const vf4*)(b_hh + c);
        vf4 bi1 = *(const vf4*)(b_ih + c + 4) + *(const vf4*)(b_hh + c + 4);
        vf4 bg0 = *(const vf4*)(b_ih + 2 * HDIM + c) + *(const vf4*)(b_hh + 2 * HDIM + c);
        vf4 bg1 = *(const vf4*)(b_ih + 2 * HDIM + c + 4) + *(const vf4*)(b_hh + 2 * HDIM + c + 4);
        vf4 bo0 = *(const vf4*)(b_ih + 3 * HDIM + c) + *(const vf4*)(b_hh + 3 * HDIM + c);
        vf4 bo1 = *(const vf4*)(b_ih + 3 * HDIM + c + 4) + *(const vf4*)(b_hh + 3 * HDIM + c + 4);
#pragma unroll
        for (int j = 0; j < 4; ++j) {
            float c0 = sigm(bi0[j]) * ftanh(bg0[j]);
            qa[j] = sigm(bo0[j]) * ftanh(c0);
            float c1 = sigm(bi1[j]) * ftanh(bg1[j]);
            qb[j] = sigm(bo1[j]) * ftanh(c1);
        }
    }

    int iters = (e - s + 3) >> 2;
    iters = max(iters, __shfl_xor(iters, 16, 64));
    iters = max(iters, __shfl_xor(iters, 32, 64));
    iters = max(iters, 1);

    AttState st;
    init_state(st);

    vf4 ca[4], cb[4];
#pragma unroll
    for (int t = 0; t < 4; ++t) {
        int rl = max(min(s + t, e - 1), 0);
        const float* xr = x + (size_t)rl * HDIM + l16 * 8;
        ca[t] = ldnt4(xr);
        cb[t] = ldnt4(xr + 4);
    }
    int base = s;
#pragma unroll 1
    for (int j = 1; j < iters; ++j) {
        vf4 na[4], nb[4];
#pragma unroll
        for (int t = 0; t < 4; ++t) {
            int rl = max(min(s + 4 * j + t, e - 1), 0);
            const float* xr = x + (size_t)rl * HDIM + l16 * 8;
            na[t] = ldnt4(xr);
            nb[t] = ldnt4(xr + 4);
        }
        // store bf16 + accumulate for rows [base, base+4)
#pragma unroll
        for (int t = 0; t < 4; ++t) {
            if (base + t < e) {
                u16x8 cv;
                cv[0] = f2bf(ca[t].x); cv[1] = f2bf(ca[t].y); cv[2] = f2bf(ca[t].z); cv[3] = f2bf(ca[t].w);
                cv[4] = f2bf(cb[t].x); cv[5] = f2bf(cb[t].y); cv[6] = f2bf(cb[t].z); cv[7] = f2bf(cb[t].w);
                *(u16x8*)(x16 + (size_t)(base + t) * HDIM + l16 * 8) = cv;
            }
        }
        compute4(ca, cb, base, e, qa, qb, st);
#pragma unroll
        for (int t = 0; t < 4; ++t) { ca[t] = na[t]; cb[t] = nb[t]; }
        base += 4;
    }
#pragma unroll
    for (int t = 0; t < 4; ++t) {
        if (base + t < e) {
            u16x8 cv;
            cv[0] = f2bf(ca[t].x); cv[1] = f2bf(ca[t].y); cv[2] = f2bf(ca[t].z); cv[3] = f2bf(ca[t].w);
            cv[4] = f2bf(cb[t].x); cv[5] = f2bf(cb[t].y); cv[6] = f2bf(cb[t].z); cv[7] = f2bf(cb[t].w);
            *(u16x8*)(x16 + (size_t)(base + t) * HDIM + l16 * 8) = cv;
        }
    }
    compute4(ca, cb, base, e, qa, qb, st);

    if (seg < B) finish_state(st, r_out + (size_t)seg * HDIM + l16 * 8);
}

// ---- passes 2,3: bf16 x attention, quarter-per-segment, pipelined.
__global__ __launch_bounds__(256) void k_attn_b16(const unsigned short* __restrict__ x16,
                                                  const float* __restrict__ q, int ldq,
                                                  const int* __restrict__ seg_start,
                                                  float* __restrict__ r_out, int ldr, int col_off,
                                                  int B, int rev) {
    int wave = threadIdx.x >> 6;
    int lane = threadIdx.x & 63;
    int l16 = lane & 15;
    int quarter = lane >> 4;
    int seg = seg_of_block(blockIdx.x, gridDim.x, rev, wave, quarter);
    int seg_c = min(seg, B - 1);
    int s = seg_start[seg_c], e = seg_start[seg_c + 1];
    if (seg >= B) { s = 0; e = 0; }

    const float* qrow = q + (size_t)seg_c * ldq + l16 * 8;
    vf4 qa = *(const vf4*)qrow;
    vf4 qb = *(const vf4*)(qrow + 4);

    int iters = (e - s + 3) >> 2;
    iters = max(iters, __shfl_xor(iters, 16, 64));
    iters = max(iters, __shfl_xor(iters, 32, 64));
    iters = max(iters, 1);

    AttState st;
    init_state(st);

    u16x8 cur[4];
#pragma unroll
    for (int t = 0; t < 4; ++t) {
        int rl = max(min(s + t, e - 1), 0);
        cur[t] = *(const u16x8*)(x16 + (size_t)rl * HDIM + l16 * 8);
    }
    int base = s;
#pragma unroll 1
    for (int j = 1; j < iters; ++j) {
        u16x8 nxt[4];
#pragma unroll
        for (int t = 0; t < 4; ++t) {
            int rl = max(min(s + 4 * j + t, e - 1), 0);
            nxt[t] = *(const u16x8*)(x16 + (size_t)rl * HDIM + l16 * 8);
        }
        vf4 xa[4], xb[4];
#pragma unroll
        for (int t = 0; t < 4; ++t) {
            xa[t] = vf4{bf2f(cur[t][0]), bf2f(cur[t][1]), bf2f(cur[t][2]), bf2f(cur[t][3])};
            xb[t] = vf4{bf2f(cur[t][4]), bf2f(cur[t][5]), bf2f(cur[t][6]), bf2f(cur[t][7])};
        }
        compute4(xa, xb, base, e, qa, qb, st);
#pragma unroll
        for (int t = 0; t < 4; ++t) cur[t] = nxt[t];
        base += 4;
    }
    {
        vf4 xa[4], xb[4];
#pragma unroll
        for (int t = 0; t < 4; ++t) {
            xa[t] = vf4{bf2f(cur[t][0]), bf2f(cur[t][1]), bf2f(cur[t][2]), bf2f(cur[t][3])};
            xb[t] = vf4{bf2f(cur[t][4]), bf2f(cur[t][5]), bf2f(cur[t][6]), bf2f(cur[t][7])};
        }
        compute4(xa, xb, base, e, qa, qb, st);
    }

    if (seg < B) finish_state(st, r_out + (size_t)seg * ldr + col_off + l16 * 8);
}

// ---- step-1 GEMM + LSTM: K=128 (r only); gh0 folded into bias; c0 recomputed.
__global__ __launch_bounds__(256) void k_gemm_lstm1(const float* __restrict__ r_prev,
                                                    const float* __restrict__ Wc,
                                                    const float* __restrict__ gh0,
                                                    const float* __restrict__ b_ih,
                                                    const float* __restrict__ b_hh,
                                                    float* __restrict__ h_new,
                                                    float* __restrict__ c_new) {
    __shared__ float As[128 * TS];
    __shared__ float Ws[64 * TS];
    int ct = blockIdx.y;
    int rb = blockIdx.x * 128;
    int tid = threadIdx.x;
    int tx = tid & 15, ty = tid >> 4;
    float acc[8][4];
#pragma unroll
    for (int i = 0; i < 8; ++i)
#pragma unroll
        for (int j = 0; j < 4; ++j) acc[i][j] = 0.0f;

    for (int kc = 0; kc < 4; ++kc) {
        int kbase = kc * 32;
#pragma unroll
        for (int i = 0; i < 4; ++i) {
            int li = tid + i * 256;
            int row = li >> 3;
            int c4 = (li & 7) * 4;
            *(vf4*)&As[row * TS + c4] = *(const vf4*)(r_prev + (size_t)(rb + row) * HDIM + kbase + c4);
        }
#pragma unroll
        for (int i = 0; i < 2; ++i) {
            int li = tid + i * 256;
            int col = li >> 3;
            int c4 = (li & 7) * 4;
            int g = ct * 16 + (col & 15) + 128 * (col >> 4);
            *(vf4*)&Ws[col * TS + c4] = *(const vf4*)(Wc + (size_t)g * 256 + 128 + kbase + c4);
        }
        __syncthreads();
#pragma unroll
        for (int k = 0; k < 32; k += 4) {
            vf4 a[8], b[4];
#pragma unroll
            for (int i = 0; i < 8; ++i) a[i] = *(vf4*)&As[(ty + 16 * i) * TS + k];
#pragma unroll
            for (int j = 0; j < 4; ++j) b[j] = *(vf4*)&Ws[(tx + 16 * j) * TS + k];
#pragma unroll
            for (int i = 0; i < 8; ++i)
#pragma unroll
                for (int j = 0; j < 4; ++j) {
                    acc[i][j] += a[i].x * b[j].x + a[i].y * b[j].y +
                                 a[i].z * b[j].z + a[i].w * b[j].w;
                }
        }
        __syncthreads();
    }
    int hidx = ct * 16 + tx;
    float bi = b_ih[hidx] + b_hh[hidx] + gh0[hidx];
    float bf = b_ih[HDIM + hidx] + b_hh[HDIM + hidx] + gh0[HDIM + hidx];
    float bg = b_ih[2 * HDIM + hidx] + b_hh[2 * HDIM + hidx] + gh0[2 * HDIM + hidx];
    float bo = b_ih[3 * HDIM + hidx] + b_hh[3 * HDIM + hidx] + gh0[3 * HDIM + hidx];
    float bi0 = b_ih[hidx] + b_hh[hidx];
    float bg0 = b_ih[2 * HDIM + hidx] + b_hh[2 * HDIM + hidx];
    float c0 = sigm(bi0) * ftanh(bg0);
#pragma unroll
    for (int i = 0; i < 8; ++i) {
        int row = rb + ty + 16 * i;
        float gi = acc[i][0] + bi;
        float gf = acc[i][1] + bf;
        float gg = acc[i][2] + bg;
        float go = acc[i][3] + bo;
        float cn = sigm(gf) * c0 + sigm(gi) * ftanh(gg);
        float hn = sigm(go) * ftanh(cn);
        c_new[(size_t)row * HDIM + hidx] = cn;
        h_new[(size_t)row * HDIM + hidx] = hn;
    }
}

// ---- step-2 GEMM + LSTM: K=256 (h | r); h written only into out[:, :128].
__global__ __launch_bounds__(256) void k_gemm_lstm(const float* __restrict__ h_prev,
                                                   const float* __restrict__ r_prev,
                                                   const float* __restrict__ c_prev,
                                                   const float* __restrict__ Wc,
                                                   const float* __restrict__ b_ih,
                                                   const float* __restrict__ b_hh,
                                                   float* __restrict__ h_mirror) {
    __shared__ float As[128 * TS];
    __shared__ float Ws[64 * TS];
    int ct = blockIdx.y;
    int rb = blockIdx.x * 128;
    int tid = threadIdx.x;
    int tx = tid & 15, ty = tid >> 4;
    float acc[8][4];
#pragma unroll
    for (int i = 0; i < 8; ++i)
#pragma unroll
        for (int j = 0; j < 4; ++j) acc[i][j] = 0.0f;

    for (int kc = 0; kc < 8; ++kc) {
        const float* src = (kc < 4) ? h_prev : r_prev;
        int kbase = (kc & 3) * 32;
#pragma unroll
        for (int i = 0; i < 4; ++i) {
            int li = tid + i * 256;
            int row = li >> 3;
            int c4 = (li & 7) * 4;
            *(vf4*)&As[row * TS + c4] = *(const vf4*)(src + (size_t)(rb + row) * HDIM + kbase + c4);
        }
#pragma unroll
        for (int i = 0; i < 2; ++i) {
            int li = tid + i * 256;
            int col = li >> 3;
            int c4 = (li & 7) * 4;
            int g = ct * 16 + (col & 15) + 128 * (col >> 4);
            *(vf4*)&Ws[col * TS + c4] = *(const vf4*)(Wc + (size_t)g * 256 + kc * 32 + c4);
        }
        __syncthreads();
#pragma unroll
        for (int k = 0; k < 32; k += 4) {
            vf4 a[8], b[4];
#pragma unroll
            for (int i = 0; i < 8; ++i) a[i] = *(vf4*)&As[(ty + 16 * i) * TS + k];
#pragma unroll
            for (int j = 0; j < 4; ++j) b[j] = *(vf4*)&Ws[(tx + 16 * j) * TS + k];
#pragma unroll
            for (int i = 0; i < 8; ++i)
#pragma unroll
                for (int j = 0; j < 4; ++j) {
                    acc[i][j] += a[i].x * b[j].x + a[i].y * b[j].y +
                                 a[i].z * b[j].z + a[i].w * b[j].w;
                }
        }
        __syncthreads();
    }
    int hidx = ct * 16 + tx;
    float bi = b_ih[hidx] + b_hh[hidx];
    float bf = b_ih[HDIM + hidx] + b_hh[HDIM + hidx];
    float bg = b_ih[2 * HDIM + hidx] + b_hh[2 * HDIM + hidx];
    float bo = b_ih[3 * HDIM + hidx] + b_hh[3 * HDIM + hidx];
#pragma unroll
    for (int i = 0; i < 8; ++i) {
        int row = rb + ty + 16 * i;
        float gi = acc[i][0] + bi;
        float gf = acc[i][1] + bf;
        float gg = acc[i][2] + bg;
        float go = acc[i][3] + bo;
        float cp = c_prev[(size_t)row * HDIM + hidx];
        float cn = sigm(gf) * cp + sigm(gi) * ftanh(gg);
        float hn = sigm(go) * ftanh(cn);
        h_mirror[(size_t)row * 2 * HDIM + hidx] = hn;
    }
}

extern "C" void kernel_launch(void* const* d_in, const int* in_sizes, int n_in,
                              void* d_out, int out_size, void* d_ws, size_t ws_size,
                              hipStream_t stream) {
    const float* x = (const float*)d_in[0];
    const int* batch_vec = (const int*)d_in[1];
    const float* W_ih = (const float*)d_in[2];
    const float* W_hh = (const float*)d_in[3];
    const float* b_ih = (const float*)d_in[4];
    const float* b_hh = (const float*)d_in[5];
    float* out = (float*)d_out;

    int N = in_sizes[1];
    int B = out_size / (2 * HDIM);

    char* ws = (char*)d_ws;
    float* Wc = (float*)ws;            ws += (size_t)G4 * 2 * HDIM * 4;
    float* gh0 = (float*)ws;           ws += (size_t)G4 * 4;
    float* h_b = (float*)ws;           ws += (size_t)B * HDIM * 4;
    float* cbuf = (float*)ws;          ws += (size_t)B * HDIM * 4;
    float* rbuf = (float*)ws;          ws += (size_t)B * HDIM * 4;
    int* seg = (int*)ws;               ws += (size_t)(B + 1) * 4;
    ws = (char*)(((size_t)ws + 255) & ~(size_t)255);
    unsigned short* x16 = (unsigned short*)ws;  // N*128*2 = 256 MB

    k_setup<<<512, 256, 0, stream>>>(W_ih, W_hh, b_ih, b_hh, batch_vec, N, B, Wc, seg, gh0);

    dim3 ggrid(B / 128, 8);
    int ablk = (B + 15) / 16;  // quarter-per-segment: 16 segments per block
    // pass 1 (fp32 + fused cvt, q0 from biases) -> GEMM1 -> pass 2 -> GEMM2 -> pass 3
    k_attn_cvt<<<ablk, 256, 0, stream>>>(x, x16, b_ih, b_hh, seg, rbuf, B);
    k_gemm_lstm1<<<ggrid, 256, 0, stream>>>(rbuf, Wc, gh0, b_ih, b_hh, h_b, cbuf);
    k_attn_b16<<<ablk, 256, 0, stream>>>(x16, h_b, HDIM, seg, rbuf, HDIM, 0, B, 1);
    k_gemm_lstm<<<ggrid, 256, 0, stream>>>(h_b, rbuf, cbuf, Wc, b_ih, b_hh, out);
    k_attn_b16<<<ablk, 256, 0, stream>>>(x16, out, 2 * HDIM, seg, out, 2 * HDIM, HDIM, B, 0);
}